// Round 4
// baseline (156.465 us; speedup 1.0000x reference)
//
#include <hip/hip_runtime.h>
#include <math.h>

#define NB 2
#define NL 2048
#define NK 30
#define NEF 128
#define NEIN 416
#define BM 64            // edges per block in k_edge

typedef _Float16 half8 __attribute__((ext_vector_type(8)));
typedef _Float16 half4 __attribute__((ext_vector_type(4)));
typedef _Float16 half2v __attribute__((ext_vector_type(2)));
typedef float f32x4 __attribute__((ext_vector_type(4)));

__constant__ int c_PA[24] = {0,2,3,4,1,1,1,1,0,0,0,4,4,3,0,2,3,4,2,3,4,2,3,2};
__constant__ int c_PB[24] = {0,2,3,4,0,2,3,4,2,3,4,2,3,2,1,1,1,1,0,0,0,4,4,3};

// ------- kernel 0: atoms5 = [N,Ca,C,O,Cb]; caw4 = packed (Ca.xyz, mask) -------
__global__ void k_atoms(const float* __restrict__ X, const float* __restrict__ mask,
                        float* __restrict__ atoms5, float4* __restrict__ caw4)
{
    int idx = blockIdx.x * blockDim.x + threadIdx.x;
    if (idx >= NB * NL) return;
    const float* x = X + (size_t)idx * 12;
    float N[3], Ca[3], C[3], O[3], bv[3], cv[3], av[3];
#pragma unroll
    for (int d = 0; d < 3; d++) { N[d] = x[d]; Ca[d] = x[3+d]; C[d] = x[6+d]; O[d] = x[9+d]; }
#pragma unroll
    for (int d = 0; d < 3; d++) { bv[d] = Ca[d] - N[d]; cv[d] = C[d] - Ca[d]; }
    av[0] = bv[1]*cv[2] - bv[2]*cv[1];
    av[1] = bv[2]*cv[0] - bv[0]*cv[2];
    av[2] = bv[0]*cv[1] - bv[1]*cv[0];
    float* o = atoms5 + (size_t)idx * 15;
#pragma unroll
    for (int d = 0; d < 3; d++) {
        o[d]      = N[d];
        o[3 + d]  = Ca[d];
        o[6 + d]  = C[d];
        o[9 + d]  = O[d];
        o[12 + d] = -0.58273431f*av[d] + 0.56802827f*bv[d] - 0.54067466f*cv[d] + Ca[d];
    }
    caw4[idx] = make_float4(Ca[0], Ca[1], Ca[2], mask[idx]);
}

// ---------------- kernel 0b: W (416x128 f32) -> Wt (128x416 f16) ----------------
__global__ void k_wconv(const float* __restrict__ eW, _Float16* __restrict__ Wt)
{
    int idx = blockIdx.x * blockDim.x + threadIdx.x;
    if (idx >= NEIN * NEF) return;
    int k = idx >> 7;
    int c = idx & 127;
    Wt[(size_t)c * NEIN + k] = (_Float16)eW[idx];
}

// ---------------- kernel 1: exact top-30, one WAVE per row ----------------
__global__ __launch_bounds__(256) void k_topk(const float4* __restrict__ caw4,
                                              float* __restrict__ dnb,
                                              int*   __restrict__ eidx,
                                              float* __restrict__ eidx_f)
{
    __shared__ float4 ca[NL];
    int t = threadIdx.x;
    int base = blockIdx.x << 2;          // 4 rows per block (one per wave)
    int b = base >> 11;
    const float4* src = caw4 + (size_t)b * NL;
#pragma unroll
    for (int r = 0; r < NL/256; r++) ca[t + r*256] = src[t + r*256];
    __syncthreads();

    int w = t >> 6, lane = t & 63;
    int row = base + w;
    int i = row & (NL - 1);
    float4 ci = ca[i];
    float mi = ci.w;

    unsigned long long key[32];
    unsigned mflags = 0;                  // bit r: m2 != 0
    float lmax = 0.0f;
#pragma unroll
    for (int r = 0; r < 32; r++) {
        float4 cj = ca[r*64 + lane];
        float dx = __fsub_rn(ci.x, cj.x);
        float dy = __fsub_rn(ci.y, cj.y);
        float dz = __fsub_rn(ci.z, cj.z);
        float s  = __fadd_rn(__fadd_rn(__fmul_rn(dx,dx), __fmul_rn(dy,dy)), __fmul_rn(dz,dz));
        s = __fadd_rn(s, 1e-6f);
        float m2 = __fmul_rn(mi, cj.w);   // binary mask: 0 or 1
        float d  = __fmul_rn(m2, __fsqrt_rn(s));
        lmax = fmaxf(lmax, d);
        mflags |= (m2 != 0.0f) ? (1u << r) : 0u;
        key[r] = ((unsigned long long)__float_as_uint(d) << 32) | (unsigned)(r*64 + lane);
    }
#pragma unroll
    for (int off = 32; off; off >>= 1) lmax = fmaxf(lmax, __shfl_xor(lmax, off));
    unsigned rmb = __float_as_uint(lmax);
#pragma unroll
    for (int r = 0; r < 32; r++) {
        bool um = (mflags >> r) & 1u;
        unsigned hi = um ? (unsigned)(key[r] >> 32) : rmb;
        key[r] = ((unsigned long long)hi << 32) | (key[r] & 0xffffffffULL);
    }

    long long last = -1LL;
    long long mykey = 0;
    for (int sel = 0; sel < NK; sel++) {
        long long best = 0x7fffffffffffffffLL;
#pragma unroll
        for (int r = 0; r < 32; r++) {
            long long k = (long long)key[r];
            bool c = (k > last) & (k < best);
            best = c ? k : best;
        }
#pragma unroll
        for (int off = 32; off; off >>= 1) {
            long long o = __shfl_xor(best, off);
            best = (o < best) ? o : best;
        }
        last = best;
        mykey = (lane == sel) ? best : mykey;
    }
    if (lane < NK) {
        int g = row * NK + lane;
        int j = (int)((unsigned long long)mykey & 0xffffffffULL);
        dnb[g]    = __uint_as_float((unsigned)((unsigned long long)mykey >> 32));
        eidx[g]   = j;
        eidx_f[g] = (float)j;
    }
}

// ------- kernel 2: features(f16) + MFMA GEMM + LayerNorm, 512 thr / 8 waves -------
// BM=64 edges, fA[64][424] f16 (54.25 KB -> 3 blocks/CU, 24 waves = 75% occ).
// Wave w: rows (w>>1)*16..+15, cols (w&1)*64..+63 (4 N-tiles of 16).
// LN: per-row stats span 2 waves -> cross-wave combine through 1KB scratch
// reused from fA after a barrier (all MFMA reads done).
__global__ __launch_bounds__(512) void k_edge(const float* __restrict__ atoms5,
                                              const int*   __restrict__ eidx,
                                              const float* __restrict__ dnb,
                                              const int*   __restrict__ ridx,
                                              const int*   __restrict__ chl,
                                              const float* __restrict__ posW,
                                              const float* __restrict__ posb,
                                              const _Float16* __restrict__ Wt,
                                              const float* __restrict__ lns,
                                              const float* __restrict__ lno,
                                              float* __restrict__ Eout)
{
    __shared__ __align__(16) _Float16 fA[BM][424];
    int t = threadIdx.x;
    int base = blockIdx.x * BM;

    // ---- phase 1: features. 8 threads per edge; thread q handles s = 2q, 2q+1
    {
        int e = t >> 3;
        int q = t & 7;
        int g = base + e;
        int b = g / (NL * NK);
        int rem = g - b * (NL * NK);
        int i = rem / NK;
        int gi = b * NL + i;
        int j = eidx[g];
        int gj = b * NL + j;

        int off = ridx[gi] - ridx[gj];
        int ec  = (chl[gi] == chl[gj]) ? 1 : 0;
        int dp  = min(max(off + 32, 0), 64);
        dp = ec ? dp : 65;
        half2v pv;
#pragma unroll
        for (int u = 0; u < 2; u++) {
            int s = q * 2 + u;
            pv[u] = (_Float16)(posW[dp * 16 + s] + posb[s]);
        }
        *(half2v*)&fA[e][q * 2] = pv;

        const float* Ai = atoms5 + (size_t)gi * 15;
        const float* Aj = atoms5 + (size_t)gj * 15;
        float D[25];
        D[0] = dnb[g];
#pragma unroll
        for (int p = 0; p < 24; p++) {
            const float* a  = Ai + c_PA[p] * 3;
            const float* bb = Aj + c_PB[p] * 3;
            float dx = a[0]-bb[0], dy = a[1]-bb[1], dz = a[2]-bb[2];
            D[p+1] = sqrtf(dx*dx + dy*dy + dz*dz + 1e-6f);
        }
        float mu0 = 2.0f + (float)(q * 2) * (20.0f / 15.0f);
#pragma unroll
        for (int p = 0; p < 25; p++) {
            half2v rv;
#pragma unroll
            for (int u = 0; u < 2; u++) {
                float mu = mu0 + (float)u * (20.0f / 15.0f);
                float z = (D[p] - mu) * 0.8f;
                rv[u] = (_Float16)__expf(-(z * z));
            }
            *(half2v*)&fA[e][16 + p * 16 + q * 2] = rv;
        }
    }
    __syncthreads();

    // ---- phase 2: MFMA GEMM. 8 waves: rows (w>>1)*16, cols (w&1)*64.
    int w    = t >> 6;
    int lane = t & 63;
    int l16  = lane & 15;
    int g8   = (lane >> 4) * 8;
    int mrow = (w >> 1) * 16;
    int ncol = (w & 1) * 64;

    f32x4 acc[4];
#pragma unroll
    for (int nt = 0; nt < 4; nt++) acc[nt] = (f32x4){0.f, 0.f, 0.f, 0.f};

    const _Float16* fArow = &fA[mrow + l16][0];
    const _Float16* wtb   = Wt + (size_t)(ncol + l16) * NEIN + g8;

    for (int kt = 0; kt < 13; kt++) {
        half8 a = *(const half8*)(fArow + kt * 32 + g8);
#pragma unroll
        for (int nt = 0; nt < 4; nt++) {
            half8 bf = *(const half8*)(wtb + (size_t)nt * 16 * NEIN + kt * 32);
            acc[nt] = __builtin_amdgcn_mfma_f32_16x16x32_f16(a, bf, acc[nt], 0, 0, 0);
        }
    }

    // ---- phase 3: LayerNorm with cross-wave (half) combine.
    float sum[4], ssq[4];
#pragma unroll
    for (int r = 0; r < 4; r++) { sum[r] = 0.f; ssq[r] = 0.f; }
#pragma unroll
    for (int nt = 0; nt < 4; nt++)
#pragma unroll
        for (int r = 0; r < 4; r++) {
            float v = acc[nt][r];
            sum[r] += v;
            ssq[r] += v * v;
        }
#pragma unroll
    for (int off = 1; off < 16; off <<= 1)
#pragma unroll
        for (int r = 0; r < 4; r++) {
            sum[r] += __shfl_xor(sum[r], off);
            ssq[r] += __shfl_xor(ssq[r], off);
        }

    __syncthreads();                        // all fA reads done -> reuse as scratch
    float* red = (float*)&fA[0][0];         // [64 rows][2 halves][2] = 256 floats
    if (l16 == 0) {
        int half = w & 1;
#pragma unroll
        for (int r = 0; r < 4; r++) {
            int row = mrow + (lane >> 4) * 4 + r;
            red[row * 4 + half * 2 + 0] = sum[r];
            red[row * 4 + half * 2 + 1] = ssq[r];
        }
    }
    __syncthreads();

    float sc[4], of[4];
#pragma unroll
    for (int nt = 0; nt < 4; nt++) {
        sc[nt] = lns[ncol + nt * 16 + l16];
        of[nt] = lno[ncol + nt * 16 + l16];
    }
#pragma unroll
    for (int r = 0; r < 4; r++) {
        int row  = mrow + (lane >> 4) * 4 + r;
        float ts = red[row * 4 + 0] + red[row * 4 + 2];
        float tq = red[row * 4 + 1] + red[row * 4 + 3];
        float mu  = ts * (1.0f / 128.0f);
        float var = tq * (1.0f / 128.0f) - mu * mu;
        float rs  = 1.0f / sqrtf(var + 1e-5f);
        int edge  = base + row;
        float* op = Eout + (size_t)edge * NEF + ncol + l16;
#pragma unroll
        for (int nt = 0; nt < 4; nt++)
            op[nt * 16] = sc[nt] * ((acc[nt][r] - mu) * rs) + of[nt];
    }
}

extern "C" void kernel_launch(void* const* d_in, const int* in_sizes, int n_in,
                              void* d_out, int out_size, void* d_ws, size_t ws_size,
                              hipStream_t stream)
{
    const float* X    = (const float*)d_in[0];
    const float* mask = (const float*)d_in[1];
    const int*   ridx = (const int*)d_in[2];
    const int*   chl  = (const int*)d_in[3];
    const float* posW = (const float*)d_in[4];
    const float* posb = (const float*)d_in[5];
    const float* eW   = (const float*)d_in[6];
    const float* lns  = (const float*)d_in[7];
    const float* lno  = (const float*)d_in[8];

    float* Eout   = (float*)d_out;                                  // B*L*K*128
    float* eidx_f = Eout + (size_t)NB * NL * NK * NEF;              // B*L*K (as float)

    char* ws = (char*)d_ws;
    float*    atoms5 = (float*)ws;                                  // 4096*15 f32
    float*    dnb    = (float*)(ws + 245760);                       // 122880 f32
    int*      eidx   = (int*)(ws + 737280);                         // 122880 i32
    _Float16* Wt     = (_Float16*)(ws + 1228800);                   // 128*416 f16
    float4*   caw4   = (float4*)(ws + 1335296);                     // 4096 float4

    k_atoms<<<(NB * NL + 255) / 256, 256, 0, stream>>>(X, mask, atoms5, caw4);
    k_wconv<<<(NEIN * NEF + 255) / 256, 256, 0, stream>>>(eW, Wt);
    k_topk<<<(NB * NL) / 4, 256, 0, stream>>>(caw4, dnb, eidx, eidx_f);
    k_edge<<<(NB * NL * NK) / BM, 512, 0, stream>>>(atoms5, eidx, dnb, ridx, chl,
                                                    posW, posb, Wt, lns, lno, Eout);
}

// Round 5
// 123.130 us; speedup vs baseline: 1.2707x; 1.2707x over previous
//
#include <hip/hip_runtime.h>
#include <math.h>

#define NB 2
#define NL 2048
#define NK 30
#define NEF 128
#define NEIN 416
#define BM 64            // edges per block in k_edge

typedef _Float16 half8 __attribute__((ext_vector_type(8)));
typedef _Float16 half4 __attribute__((ext_vector_type(4)));
typedef _Float16 half2v __attribute__((ext_vector_type(2)));
typedef float f32x4 __attribute__((ext_vector_type(4)));

__constant__ int c_PA[24] = {0,2,3,4,1,1,1,1,0,0,0,4,4,3,0,2,3,4,2,3,4,2,3,2};
__constant__ int c_PB[24] = {0,2,3,4,0,2,3,4,2,3,4,2,3,2,1,1,1,1,0,0,0,4,4,3};

// ------- kernel 0: atoms5 = [N,Ca,C,O,Cb]; caw4 = packed (Ca.xyz, mask) -------
__global__ void k_atoms(const float* __restrict__ X, const float* __restrict__ mask,
                        float* __restrict__ atoms5, float4* __restrict__ caw4)
{
    int idx = blockIdx.x * blockDim.x + threadIdx.x;
    if (idx >= NB * NL) return;
    const float* x = X + (size_t)idx * 12;
    float N[3], Ca[3], C[3], O[3], bv[3], cv[3], av[3];
#pragma unroll
    for (int d = 0; d < 3; d++) { N[d] = x[d]; Ca[d] = x[3+d]; C[d] = x[6+d]; O[d] = x[9+d]; }
#pragma unroll
    for (int d = 0; d < 3; d++) { bv[d] = Ca[d] - N[d]; cv[d] = C[d] - Ca[d]; }
    av[0] = bv[1]*cv[2] - bv[2]*cv[1];
    av[1] = bv[2]*cv[0] - bv[0]*cv[2];
    av[2] = bv[0]*cv[1] - bv[1]*cv[0];
    float* o = atoms5 + (size_t)idx * 15;
#pragma unroll
    for (int d = 0; d < 3; d++) {
        o[d]      = N[d];
        o[3 + d]  = Ca[d];
        o[6 + d]  = C[d];
        o[9 + d]  = O[d];
        o[12 + d] = -0.58273431f*av[d] + 0.56802827f*bv[d] - 0.54067466f*cv[d] + Ca[d];
    }
    caw4[idx] = make_float4(Ca[0], Ca[1], Ca[2], mask[idx]);
}

// ---------------- kernel 0b: W (416x128 f32) -> Wt (128x416 f16) ----------------
__global__ void k_wconv(const float* __restrict__ eW, _Float16* __restrict__ Wt)
{
    int idx = blockIdx.x * blockDim.x + threadIdx.x;
    if (idx >= NEIN * NEF) return;
    int k = idx >> 7;
    int c = idx & 127;
    Wt[(size_t)c * NEIN + k] = (_Float16)eW[idx];
}

// ---------------- kernel 1: exact top-30, one WAVE per row ----------------
__global__ __launch_bounds__(256) void k_topk(const float4* __restrict__ caw4,
                                              float* __restrict__ dnb,
                                              int*   __restrict__ eidx,
                                              float* __restrict__ eidx_f)
{
    __shared__ float4 ca[NL];
    int t = threadIdx.x;
    int base = blockIdx.x << 2;          // 4 rows per block (one per wave)
    int b = base >> 11;
    const float4* src = caw4 + (size_t)b * NL;
#pragma unroll
    for (int r = 0; r < NL/256; r++) ca[t + r*256] = src[t + r*256];
    __syncthreads();

    int w = t >> 6, lane = t & 63;
    int row = base + w;
    int i = row & (NL - 1);
    float4 ci = ca[i];
    float mi = ci.w;

    unsigned long long key[32];
    unsigned mflags = 0;                  // bit r: m2 != 0
    float lmax = 0.0f;
#pragma unroll
    for (int r = 0; r < 32; r++) {
        float4 cj = ca[r*64 + lane];
        float dx = __fsub_rn(ci.x, cj.x);
        float dy = __fsub_rn(ci.y, cj.y);
        float dz = __fsub_rn(ci.z, cj.z);
        float s  = __fadd_rn(__fadd_rn(__fmul_rn(dx,dx), __fmul_rn(dy,dy)), __fmul_rn(dz,dz));
        s = __fadd_rn(s, 1e-6f);
        float m2 = __fmul_rn(mi, cj.w);   // binary mask: 0 or 1
        float d  = __fmul_rn(m2, __fsqrt_rn(s));
        lmax = fmaxf(lmax, d);
        mflags |= (m2 != 0.0f) ? (1u << r) : 0u;
        key[r] = ((unsigned long long)__float_as_uint(d) << 32) | (unsigned)(r*64 + lane);
    }
#pragma unroll
    for (int off = 32; off; off >>= 1) lmax = fmaxf(lmax, __shfl_xor(lmax, off));
    unsigned rmb = __float_as_uint(lmax);
#pragma unroll
    for (int r = 0; r < 32; r++) {
        bool um = (mflags >> r) & 1u;
        unsigned hi = um ? (unsigned)(key[r] >> 32) : rmb;
        key[r] = ((unsigned long long)hi << 32) | (key[r] & 0xffffffffULL);
    }

    long long last = -1LL;
    long long mykey = 0;
    for (int sel = 0; sel < NK; sel++) {
        long long best = 0x7fffffffffffffffLL;
#pragma unroll
        for (int r = 0; r < 32; r++) {
            long long k = (long long)key[r];
            bool c = (k > last) & (k < best);
            best = c ? k : best;
        }
#pragma unroll
        for (int off = 32; off; off >>= 1) {
            long long o = __shfl_xor(best, off);
            best = (o < best) ? o : best;
        }
        last = best;
        mykey = (lane == sel) ? best : mykey;
    }
    if (lane < NK) {
        int g = row * NK + lane;
        int j = (int)((unsigned long long)mykey & 0xffffffffULL);
        dnb[g]    = __uint_as_float((unsigned)((unsigned long long)mykey >> 32));
        eidx[g]   = j;
        eidx_f[g] = (float)j;
    }
}

// ------- kernel 2: features(f16) + MFMA GEMM + LayerNorm, 512 thr / 8 waves -------
// Wave w: ALL 64 rows (mt=4), cols w*16..+15 (nt=1). B fragments (13 x half8 =
// 52 VGPR) preloaded in one burst BEFORE the feature phase: L2 latency hides
// under the transcendental-heavy feature compute; each B frag feeds 4 MFMAs.
// GEMM inner loop = pure ds_read_b128 + MFMA (no global ops).
__global__ __launch_bounds__(512, 4) void k_edge(const float* __restrict__ atoms5,
                                              const int*   __restrict__ eidx,
                                              const float* __restrict__ dnb,
                                              const int*   __restrict__ ridx,
                                              const int*   __restrict__ chl,
                                              const float* __restrict__ posW,
                                              const float* __restrict__ posb,
                                              const _Float16* __restrict__ Wt,
                                              const float* __restrict__ lns,
                                              const float* __restrict__ lno,
                                              float* __restrict__ Eout)
{
    __shared__ __align__(16) _Float16 fA[BM][424];   // 54272 B
    int t = threadIdx.x;
    int base = blockIdx.x * BM;

    int w    = t >> 6;
    int lane = t & 63;
    int l16  = lane & 15;
    int g8   = (lane >> 4) * 8;
    int ncol = w * 16;

    // ---- B preload: 13 independent 16B loads, latency hidden by phase 1.
    const _Float16* wtb = Wt + (size_t)(ncol + l16) * NEIN + g8;
    half8 bfr[13];
#pragma unroll
    for (int kt = 0; kt < 13; kt++)
        bfr[kt] = *(const half8*)(wtb + kt * 32);

    // ---- phase 1: features. 8 threads per edge; thread q handles s = 2q, 2q+1
    {
        int e = t >> 3;
        int q = t & 7;
        int g = base + e;
        int b = g / (NL * NK);
        int rem = g - b * (NL * NK);
        int i = rem / NK;
        int gi = b * NL + i;
        int j = eidx[g];
        int gj = b * NL + j;

        int off = ridx[gi] - ridx[gj];
        int ec  = (chl[gi] == chl[gj]) ? 1 : 0;
        int dp  = min(max(off + 32, 0), 64);
        dp = ec ? dp : 65;
        half2v pv;
#pragma unroll
        for (int u = 0; u < 2; u++) {
            int s = q * 2 + u;
            pv[u] = (_Float16)(posW[dp * 16 + s] + posb[s]);
        }
        *(half2v*)&fA[e][q * 2] = pv;

        const float* Ai = atoms5 + (size_t)gi * 15;
        const float* Aj = atoms5 + (size_t)gj * 15;
        float D[25];
        D[0] = dnb[g];
#pragma unroll
        for (int p = 0; p < 24; p++) {
            const float* a  = Ai + c_PA[p] * 3;
            const float* bb = Aj + c_PB[p] * 3;
            float dx = a[0]-bb[0], dy = a[1]-bb[1], dz = a[2]-bb[2];
            D[p+1] = sqrtf(dx*dx + dy*dy + dz*dz + 1e-6f);
        }
        float mu0 = 2.0f + (float)(q * 2) * (20.0f / 15.0f);
#pragma unroll
        for (int p = 0; p < 25; p++) {
            half2v rv;
#pragma unroll
            for (int u = 0; u < 2; u++) {
                float mu = mu0 + (float)u * (20.0f / 15.0f);
                float z = (D[p] - mu) * 0.8f;
                rv[u] = (_Float16)__expf(-(z * z));
            }
            *(half2v*)&fA[e][16 + p * 16 + q * 2] = rv;
        }
    }
    __syncthreads();

    // ---- phase 2: GEMM. 52 MFMA + 52 ds_read_b128 per wave, zero global ops.
    f32x4 acc[4];
#pragma unroll
    for (int mt = 0; mt < 4; mt++) acc[mt] = (f32x4){0.f, 0.f, 0.f, 0.f};

#pragma unroll
    for (int kt = 0; kt < 13; kt++) {
#pragma unroll
        for (int mt = 0; mt < 4; mt++) {
            half8 a = *(const half8*)(&fA[mt * 16 + l16][kt * 32 + g8]);
            acc[mt] = __builtin_amdgcn_mfma_f32_16x16x32_f16(a, bfr[kt], acc[mt], 0, 0, 0);
        }
    }

    // ---- phase 3: LayerNorm. Reduce 16 cols in-wave, combine 8 waves via LDS.
    float sum[4][4], ssq[4][4];
#pragma unroll
    for (int mt = 0; mt < 4; mt++)
#pragma unroll
        for (int r = 0; r < 4; r++) {
            float v = acc[mt][r];
            sum[mt][r] = v;
            ssq[mt][r] = v * v;
        }
#pragma unroll
    for (int off = 1; off < 16; off <<= 1)
#pragma unroll
        for (int mt = 0; mt < 4; mt++)
#pragma unroll
            for (int r = 0; r < 4; r++) {
                sum[mt][r] += __shfl_xor(sum[mt][r], off);
                ssq[mt][r] += __shfl_xor(ssq[mt][r], off);
            }

    __syncthreads();                        // all fA reads done -> reuse as scratch
    float* red  = (float*)&fA[0][0];        // [64 rows][8 waves][2] = 4 KB
    float* red2 = red + 1024;               // [64 rows][2]
    if (l16 == 0) {
        int lg = lane >> 4;
#pragma unroll
        for (int mt = 0; mt < 4; mt++)
#pragma unroll
            for (int r = 0; r < 4; r++) {
                int row = mt * 16 + lg * 4 + r;
                red[(row * 8 + w) * 2 + 0] = sum[mt][r];
                red[(row * 8 + w) * 2 + 1] = ssq[mt][r];
            }
    }
    __syncthreads();
    if (t < 64) {
        float ts = 0.f, tq = 0.f;
#pragma unroll
        for (int u = 0; u < 8; u++) {
            ts += red[(t * 8 + u) * 2 + 0];
            tq += red[(t * 8 + u) * 2 + 1];
        }
        float mu  = ts * (1.0f / 128.0f);
        float var = tq * (1.0f / 128.0f) - mu * mu;
        red2[t * 2 + 0] = mu;
        red2[t * 2 + 1] = 1.0f / sqrtf(var + 1e-5f);
    }
    __syncthreads();

    float sc = lns[ncol + l16];
    float of = lno[ncol + l16];
    int lg = lane >> 4;
#pragma unroll
    for (int mt = 0; mt < 4; mt++)
#pragma unroll
        for (int r = 0; r < 4; r++) {
            int row = mt * 16 + lg * 4 + r;
            float mu = red2[row * 2 + 0];
            float rs = red2[row * 2 + 1];
            Eout[(size_t)(base + row) * NEF + ncol + l16] =
                sc * ((acc[mt][r] - mu) * rs) + of;
        }
}

extern "C" void kernel_launch(void* const* d_in, const int* in_sizes, int n_in,
                              void* d_out, int out_size, void* d_ws, size_t ws_size,
                              hipStream_t stream)
{
    const float* X    = (const float*)d_in[0];
    const float* mask = (const float*)d_in[1];
    const int*   ridx = (const int*)d_in[2];
    const int*   chl  = (const int*)d_in[3];
    const float* posW = (const float*)d_in[4];
    const float* posb = (const float*)d_in[5];
    const float* eW   = (const float*)d_in[6];
    const float* lns  = (const float*)d_in[7];
    const float* lno  = (const float*)d_in[8];

    float* Eout   = (float*)d_out;                                  // B*L*K*128
    float* eidx_f = Eout + (size_t)NB * NL * NK * NEF;              // B*L*K (as float)

    char* ws = (char*)d_ws;
    float*    atoms5 = (float*)ws;                                  // 4096*15 f32
    float*    dnb    = (float*)(ws + 245760);                       // 122880 f32
    int*      eidx   = (int*)(ws + 737280);                         // 122880 i32
    _Float16* Wt     = (_Float16*)(ws + 1228800);                   // 128*416 f16
    float4*   caw4   = (float4*)(ws + 1335296);                     // 4096 float4

    k_atoms<<<(NB * NL + 255) / 256, 256, 0, stream>>>(X, mask, atoms5, caw4);
    k_wconv<<<(NEIN * NEF + 255) / 256, 256, 0, stream>>>(eW, Wt);
    k_topk<<<(NB * NL) / 4, 256, 0, stream>>>(caw4, dnb, eidx, eidx_f);
    k_edge<<<(NB * NL * NK) / BM, 512, 0, stream>>>(atoms5, eidx, dnb, ridx, chl,
                                                    posW, posb, Wt, lns, lno, Eout);
}

// Round 6
// 122.229 us; speedup vs baseline: 1.2801x; 1.0074x over previous
//
#include <hip/hip_runtime.h>
#include <math.h>

#define NB 2
#define NL 2048
#define NK 30
#define NEF 128
#define NEIN 416
#define BM 64            // edges per block in k_edge

typedef _Float16 half16 __attribute__((ext_vector_type(16)));
typedef _Float16 half8 __attribute__((ext_vector_type(8)));
typedef _Float16 half2v __attribute__((ext_vector_type(2)));
typedef float f32x4 __attribute__((ext_vector_type(4)));

__constant__ int c_PA[24] = {0,2,3,4,1,1,1,1,0,0,0,4,4,3,0,2,3,4,2,3,4,2,3,2};
__constant__ int c_PB[24] = {0,2,3,4,0,2,3,4,2,3,4,2,3,2,1,1,1,1,0,0,0,4,4,3};

// ---- kernel 0: atoms5 = [N,Ca,C,O,Cb] as 5x float4 per residue; caw4 = (Ca.xyz, mask)
__global__ void k_atoms(const float* __restrict__ X, const float* __restrict__ mask,
                        float4* __restrict__ atoms5, float4* __restrict__ caw4)
{
    int idx = blockIdx.x * blockDim.x + threadIdx.x;
    if (idx >= NB * NL) return;
    const float* x = X + (size_t)idx * 12;
    float N[3], Ca[3], C[3], O[3], bv[3], cv[3], av[3];
#pragma unroll
    for (int d = 0; d < 3; d++) { N[d] = x[d]; Ca[d] = x[3+d]; C[d] = x[6+d]; O[d] = x[9+d]; }
#pragma unroll
    for (int d = 0; d < 3; d++) { bv[d] = Ca[d] - N[d]; cv[d] = C[d] - Ca[d]; }
    av[0] = bv[1]*cv[2] - bv[2]*cv[1];
    av[1] = bv[2]*cv[0] - bv[0]*cv[2];
    av[2] = bv[0]*cv[1] - bv[1]*cv[0];
    float4* o = atoms5 + (size_t)idx * 5;
    o[0] = make_float4(N[0], N[1], N[2], 0.f);
    o[1] = make_float4(Ca[0], Ca[1], Ca[2], 0.f);
    o[2] = make_float4(C[0], C[1], C[2], 0.f);
    o[3] = make_float4(O[0], O[1], O[2], 0.f);
    float cb0 = -0.58273431f*av[0] + 0.56802827f*bv[0] - 0.54067466f*cv[0] + Ca[0];
    float cb1 = -0.58273431f*av[1] + 0.56802827f*bv[1] - 0.54067466f*cv[1] + Ca[1];
    float cb2 = -0.58273431f*av[2] + 0.56802827f*bv[2] - 0.54067466f*cv[2] + Ca[2];
    o[4] = make_float4(cb0, cb1, cb2, 0.f);
    caw4[idx] = make_float4(Ca[0], Ca[1], Ca[2], mask[idx]);
}

// ---------------- kernel 0b: W (416x128 f32) -> Wt (128x416 f16) ----------------
__global__ void k_wconv(const float* __restrict__ eW, _Float16* __restrict__ Wt)
{
    int idx = blockIdx.x * blockDim.x + threadIdx.x;
    if (idx >= NEIN * NEF) return;
    int k = idx >> 7;
    int c = idx & 127;
    Wt[(size_t)c * NEIN + k] = (_Float16)eW[idx];
}

// ---------------- kernel 1: exact top-30, one WAVE per row ----------------
__global__ __launch_bounds__(256) void k_topk(const float4* __restrict__ caw4,
                                              float* __restrict__ dnb,
                                              int*   __restrict__ eidx,
                                              float* __restrict__ eidx_f)
{
    __shared__ float4 ca[NL];
    int t = threadIdx.x;
    int base = blockIdx.x << 2;          // 4 rows per block (one per wave)
    int b = base >> 11;
    const float4* src = caw4 + (size_t)b * NL;
#pragma unroll
    for (int r = 0; r < NL/256; r++) ca[t + r*256] = src[t + r*256];
    __syncthreads();

    int w = t >> 6, lane = t & 63;
    int row = base + w;
    int i = row & (NL - 1);
    float4 ci = ca[i];
    float mi = ci.w;

    unsigned long long key[32];
    unsigned mflags = 0;                  // bit r: m2 != 0
    float lmax = 0.0f;
#pragma unroll
    for (int r = 0; r < 32; r++) {
        float4 cj = ca[r*64 + lane];
        float dx = __fsub_rn(ci.x, cj.x);
        float dy = __fsub_rn(ci.y, cj.y);
        float dz = __fsub_rn(ci.z, cj.z);
        float s  = __fadd_rn(__fadd_rn(__fmul_rn(dx,dx), __fmul_rn(dy,dy)), __fmul_rn(dz,dz));
        s = __fadd_rn(s, 1e-6f);
        float m2 = __fmul_rn(mi, cj.w);   // binary mask: 0 or 1
        float d  = __fmul_rn(m2, __fsqrt_rn(s));
        lmax = fmaxf(lmax, d);
        mflags |= (m2 != 0.0f) ? (1u << r) : 0u;
        key[r] = ((unsigned long long)__float_as_uint(d) << 32) | (unsigned)(r*64 + lane);
    }
#pragma unroll
    for (int off = 32; off; off >>= 1) lmax = fmaxf(lmax, __shfl_xor(lmax, off));
    unsigned rmb = __float_as_uint(lmax);
#pragma unroll
    for (int r = 0; r < 32; r++) {
        bool um = (mflags >> r) & 1u;
        unsigned hi = um ? (unsigned)(key[r] >> 32) : rmb;
        key[r] = ((unsigned long long)hi << 32) | (key[r] & 0xffffffffULL);
    }

    long long last = -1LL;
    long long mykey = 0;
    for (int sel = 0; sel < NK; sel++) {
        long long best = 0x7fffffffffffffffLL;
#pragma unroll
        for (int r = 0; r < 32; r++) {
            long long k = (long long)key[r];
            bool c = (k > last) & (k < best);
            best = c ? k : best;
        }
#pragma unroll
        for (int off = 32; off; off >>= 1) {
            long long o = __shfl_xor(best, off);
            best = (o < best) ? o : best;
        }
        last = best;
        mykey = (lane == sel) ? best : mykey;
    }
    if (lane < NK) {
        int g = row * NK + lane;
        int j = (int)((unsigned long long)mykey & 0xffffffffULL);
        dnb[g]    = __uint_as_float((unsigned)((unsigned long long)mykey >> 32));
        eidx[g]   = j;
        eidx_f[g] = (float)j;
    }
}

// ------- kernel 2: features(f16) + MFMA GEMM + LayerNorm, 512 thr / 8 waves -------
// Phase 1 split by DISTANCE index p (no duplicated distance math): thread q of
// edge e computes D[p] for p in {q, q+8, q+16} (+24 for q==0), then all 16 RBF
// bins of each p, written as one contiguous 32B LDS store.
// Wave w: ALL 64 rows (mt=4), cols w*16..+15. B fragments (13 x half8) preloaded
// before phase 1 so their L2 latency hides under feature compute.
__global__ __launch_bounds__(512, 4) void k_edge(const float4* __restrict__ atoms5,
                                              const int*   __restrict__ eidx,
                                              const float* __restrict__ dnb,
                                              const int*   __restrict__ ridx,
                                              const int*   __restrict__ chl,
                                              const float* __restrict__ posW,
                                              const float* __restrict__ posb,
                                              const _Float16* __restrict__ Wt,
                                              const float* __restrict__ lns,
                                              const float* __restrict__ lno,
                                              float* __restrict__ Eout)
{
    __shared__ __align__(16) _Float16 fA[BM][424];   // 54272 B
    int t = threadIdx.x;
    int base = blockIdx.x * BM;

    int w    = t >> 6;
    int lane = t & 63;
    int l16  = lane & 15;
    int g8   = (lane >> 4) * 8;
    int ncol = w * 16;

    // ---- B preload: 13 independent 16B loads, latency hidden by phase 1.
    const _Float16* wtb = Wt + (size_t)(ncol + l16) * NEIN + g8;
    half8 bfr[13];
#pragma unroll
    for (int kt = 0; kt < 13; kt++)
        bfr[kt] = *(const half8*)(wtb + kt * 32);

    // ---- phase 1: features, p-split.
    {
        int e = t >> 3;
        int q = t & 7;
        int g = base + e;
        int b = g / (NL * NK);
        int rem = g - b * (NL * NK);
        int i = rem / NK;
        int gi = b * NL + i;
        int j = eidx[g];
        int gj = b * NL + j;

        // pos features: thread q writes s = 2q, 2q+1
        int off = ridx[gi] - ridx[gj];
        int ec  = (chl[gi] == chl[gj]) ? 1 : 0;
        int dp  = min(max(off + 32, 0), 64);
        dp = ec ? dp : 65;
        half2v pv;
#pragma unroll
        for (int u = 0; u < 2; u++) {
            int s = q * 2 + u;
            pv[u] = (_Float16)(posW[dp * 16 + s] + posb[s]);
        }
        *(half2v*)&fA[e][q * 2] = pv;

        const float4* A4 = atoms5 + (size_t)gi * 5;
        const float4* B4 = atoms5 + (size_t)gj * 5;

        auto body = [&](int p) {
            float D;
            if (p == 0) {
                D = dnb[g];
            } else {
                float4 a  = A4[c_PA[p - 1]];
                float4 bb = B4[c_PB[p - 1]];
                float dx = a.x - bb.x, dy = a.y - bb.y, dz = a.z - bb.z;
                D = sqrtf(dx*dx + dy*dy + dz*dz + 1e-6f);
            }
            float tD = D * 0.8f;                  // prescale: z = tD - mu*0.8
            half16 rv;
#pragma unroll
            for (int s = 0; s < 16; s++) {
                float z = tD - (1.6f + (float)s * 1.06666667f);
                rv[s] = (_Float16)__expf(-(z * z));
            }
            *(half16*)&fA[e][16 + p * 16] = rv;   // 32B contiguous
        };

#pragma unroll
        for (int pp = 0; pp < 3; pp++) body(q + pp * 8);
        if (q == 0) body(24);
    }
    __syncthreads();

    // ---- phase 2: GEMM. 52 MFMA + 52 ds_read_b128 per wave, zero global ops.
    f32x4 acc[4];
#pragma unroll
    for (int mt = 0; mt < 4; mt++) acc[mt] = (f32x4){0.f, 0.f, 0.f, 0.f};

#pragma unroll
    for (int kt = 0; kt < 13; kt++) {
#pragma unroll
        for (int mt = 0; mt < 4; mt++) {
            half8 a = *(const half8*)(&fA[mt * 16 + l16][kt * 32 + g8]);
            acc[mt] = __builtin_amdgcn_mfma_f32_16x16x32_f16(a, bfr[kt], acc[mt], 0, 0, 0);
        }
    }

    // ---- phase 3: LayerNorm. Reduce 16 cols in-wave, combine 8 waves via LDS.
    float sum[4][4], ssq[4][4];
#pragma unroll
    for (int mt = 0; mt < 4; mt++)
#pragma unroll
        for (int r = 0; r < 4; r++) {
            float v = acc[mt][r];
            sum[mt][r] = v;
            ssq[mt][r] = v * v;
        }
#pragma unroll
    for (int off = 1; off < 16; off <<= 1)
#pragma unroll
        for (int mt = 0; mt < 4; mt++)
#pragma unroll
            for (int r = 0; r < 4; r++) {
                sum[mt][r] += __shfl_xor(sum[mt][r], off);
                ssq[mt][r] += __shfl_xor(ssq[mt][r], off);
            }

    __syncthreads();                        // all fA reads done -> reuse as scratch
    float* red  = (float*)&fA[0][0];        // [64 rows][8 waves][2] = 4 KB
    float* red2 = red + 1024;               // [64 rows][2]
    if (l16 == 0) {
        int lg = lane >> 4;
#pragma unroll
        for (int mt = 0; mt < 4; mt++)
#pragma unroll
            for (int r = 0; r < 4; r++) {
                int row = mt * 16 + lg * 4 + r;
                red[(row * 8 + w) * 2 + 0] = sum[mt][r];
                red[(row * 8 + w) * 2 + 1] = ssq[mt][r];
            }
    }
    __syncthreads();
    if (t < 64) {
        float ts = 0.f, tq = 0.f;
#pragma unroll
        for (int u = 0; u < 8; u++) {
            ts += red[(t * 8 + u) * 2 + 0];
            tq += red[(t * 8 + u) * 2 + 1];
        }
        float mu  = ts * (1.0f / 128.0f);
        float var = tq * (1.0f / 128.0f) - mu * mu;
        red2[t * 2 + 0] = mu;
        red2[t * 2 + 1] = 1.0f / sqrtf(var + 1e-5f);
    }
    __syncthreads();

    float sc = lns[ncol + l16];
    float of = lno[ncol + l16];
    int lg = lane >> 4;
#pragma unroll
    for (int mt = 0; mt < 4; mt++)
#pragma unroll
        for (int r = 0; r < 4; r++) {
            int row = mt * 16 + lg * 4 + r;
            float mu = red2[row * 2 + 0];
            float rs = red2[row * 2 + 1];
            Eout[(size_t)(base + row) * NEF + ncol + l16] =
                sc * ((acc[mt][r] - mu) * rs) + of;
        }
}

extern "C" void kernel_launch(void* const* d_in, const int* in_sizes, int n_in,
                              void* d_out, int out_size, void* d_ws, size_t ws_size,
                              hipStream_t stream)
{
    const float* X    = (const float*)d_in[0];
    const float* mask = (const float*)d_in[1];
    const int*   ridx = (const int*)d_in[2];
    const int*   chl  = (const int*)d_in[3];
    const float* posW = (const float*)d_in[4];
    const float* posb = (const float*)d_in[5];
    const float* eW   = (const float*)d_in[6];
    const float* lns  = (const float*)d_in[7];
    const float* lno  = (const float*)d_in[8];

    float* Eout   = (float*)d_out;                                  // B*L*K*128
    float* eidx_f = Eout + (size_t)NB * NL * NK * NEF;              // B*L*K (as float)

    char* ws = (char*)d_ws;
    float4*   atoms5 = (float4*)ws;                                 // 4096*5 float4 = 327680 B
    float*    dnb    = (float*)(ws + 327680);                       // 122880 f32
    int*      eidx   = (int*)(ws + 819200);                         // 122880 i32
    _Float16* Wt     = (_Float16*)(ws + 1310720);                   // 128*416 f16
    float4*   caw4   = (float4*)(ws + 1417216);                     // 4096 float4

    k_atoms<<<(NB * NL + 255) / 256, 256, 0, stream>>>(X, mask, atoms5, caw4);
    k_wconv<<<(NEIN * NEF + 255) / 256, 256, 0, stream>>>(eW, Wt);
    k_topk<<<(NB * NL) / 4, 256, 0, stream>>>(caw4, dnb, eidx, eidx_f);
    k_edge<<<(NB * NL * NK) / BM, 512, 0, stream>>>(atoms5, eidx, dnb, ridx, chl,
                                                    posW, posb, Wt, lns, lno, Eout);
}

// Round 7
// 111.028 us; speedup vs baseline: 1.4092x; 1.1009x over previous
//
#include <hip/hip_runtime.h>
#include <math.h>

#define NB 2
#define NL 2048
#define NK 30
#define NEF 128
#define NEIN 416
#define BM 64            // edges per block in k_edge
#define FROW 432         // fA row stride (bytes): 16B-aligned, bank-uniform

typedef float f32x4 __attribute__((ext_vector_type(4)));
typedef unsigned long long ull;

__constant__ int c_PA[24] = {0,2,3,4,1,1,1,1,0,0,0,4,4,3,0,2,3,4,2,3,4,2,3,2};
__constant__ int c_PB[24] = {0,2,3,4,0,2,3,4,2,3,4,2,3,2,1,1,1,1,0,0,0,4,4,3};

__device__ inline ull umin64(ull a, ull b) { return a < b ? a : b; }
__device__ inline ull umax64(ull a, ull b) { return a > b ? a : b; }

// ---- kernel 0: atoms5 = [N,Ca,C,O,Cb] as 5x float4 per residue; caw4 = (Ca.xyz, mask)
__global__ void k_atoms(const float* __restrict__ X, const float* __restrict__ mask,
                        float4* __restrict__ atoms5, float4* __restrict__ caw4)
{
    int idx = blockIdx.x * blockDim.x + threadIdx.x;
    if (idx >= NB * NL) return;
    const float* x = X + (size_t)idx * 12;
    float N[3], Ca[3], C[3], O[3], bv[3], cv[3], av[3];
#pragma unroll
    for (int d = 0; d < 3; d++) { N[d] = x[d]; Ca[d] = x[3+d]; C[d] = x[6+d]; O[d] = x[9+d]; }
#pragma unroll
    for (int d = 0; d < 3; d++) { bv[d] = Ca[d] - N[d]; cv[d] = C[d] - Ca[d]; }
    av[0] = bv[1]*cv[2] - bv[2]*cv[1];
    av[1] = bv[2]*cv[0] - bv[0]*cv[2];
    av[2] = bv[0]*cv[1] - bv[1]*cv[0];
    float4* o = atoms5 + (size_t)idx * 5;
    o[0] = make_float4(N[0], N[1], N[2], 0.f);
    o[1] = make_float4(Ca[0], Ca[1], Ca[2], 0.f);
    o[2] = make_float4(C[0], C[1], C[2], 0.f);
    o[3] = make_float4(O[0], O[1], O[2], 0.f);
    float cb0 = -0.58273431f*av[0] + 0.56802827f*bv[0] - 0.54067466f*cv[0] + Ca[0];
    float cb1 = -0.58273431f*av[1] + 0.56802827f*bv[1] - 0.54067466f*cv[1] + Ca[1];
    float cb2 = -0.58273431f*av[2] + 0.56802827f*bv[2] - 0.54067466f*cv[2] + Ca[2];
    o[4] = make_float4(cb0, cb1, cb2, 0.f);
    caw4[idx] = make_float4(Ca[0], Ca[1], Ca[2], mask[idx]);
}

// ---- kernel 0b: W (416x128 f32) -> Wt (128x416 fp8 e4m3) ----
__global__ void k_wconv(const float* __restrict__ eW, unsigned char* __restrict__ Wt)
{
    int idx = blockIdx.x * blockDim.x + threadIdx.x;
    if (idx >= NEF * (NEIN / 2)) return;
    int c  = idx / (NEIN / 2);
    int k2 = idx - c * (NEIN / 2);
    float a = eW[(size_t)(2 * k2) * NEF + c];
    float b = eW[(size_t)(2 * k2 + 1) * NEF + c];
    int r = __builtin_amdgcn_cvt_pk_fp8_f32(a, b, 0, false);
    *(unsigned short*)&Wt[(size_t)c * NEIN + 2 * k2] = (unsigned short)(r & 0xffff);
}

// ---- kernel 1: exact top-30, one WAVE per row, streaming 4-slot min-list ----
// Lane streams its 32 candidates (key = bits(D_adjust)<<32 | j, exact __f*_rn
// chain) into a sorted 4-slot register list. 30 selections = 64-bit shfl-min
// butterfly + O(1) pop. Rare capacity overflow (lane popped all 4, has more)
// triggers an exact per-lane rescan. Bit-identical ordering vs the reference.
__global__ __launch_bounds__(256, 8) void k_topk(const float4* __restrict__ caw4,
                                                 float* __restrict__ dnb,
                                                 int*   __restrict__ eidx,
                                                 float* __restrict__ eidx_f)
{
    __shared__ float4 ca[NL];
    int t = threadIdx.x;
    int base = blockIdx.x << 2;          // 4 rows per block (one per wave)
    int b = base >> 11;
    const float4* src = caw4 + (size_t)b * NL;
#pragma unroll
    for (int r = 0; r < NL/256; r++) ca[t + r*256] = src[t + r*256];
    __syncthreads();

    int w = t >> 6, lane = t & 63;
    int row = base + w;
    int i = row & (NL - 1);
    float4 ci = ca[i];
    float mi = ci.w;

    // pass 1: distances (exact chain), keep in regs, row max for masked keys
    float df[32];
    unsigned mflags = 0;
    float lmax = 0.0f;
#pragma unroll
    for (int r = 0; r < 32; r++) {
        float4 cj = ca[r*64 + lane];
        float dx = __fsub_rn(ci.x, cj.x);
        float dy = __fsub_rn(ci.y, cj.y);
        float dz = __fsub_rn(ci.z, cj.z);
        float s  = __fadd_rn(__fadd_rn(__fmul_rn(dx,dx), __fmul_rn(dy,dy)), __fmul_rn(dz,dz));
        s = __fadd_rn(s, 1e-6f);
        float m2 = __fmul_rn(mi, cj.w);   // binary mask: 0 or 1
        float d  = __fmul_rn(m2, __fsqrt_rn(s));
        df[r] = d;
        lmax = fmaxf(lmax, d);
        mflags |= (m2 != 0.0f) ? (1u << r) : 0u;
    }
#pragma unroll
    for (int off = 32; off; off >>= 1) lmax = fmaxf(lmax, __shfl_xor(lmax, off));
    unsigned rmb = __float_as_uint(lmax);

    // pass 2: stream all 32 keys into sorted 4-slot min list
    const ull INF = ~0ULL;
    ull m0 = INF, m1 = INF, m2k = INF, m3 = INF;
#pragma unroll
    for (int r = 0; r < 32; r++) {
        unsigned hi = ((mflags >> r) & 1u) ? __float_as_uint(df[r]) : rmb;
        ull key = ((ull)hi << 32) | (unsigned)(r*64 + lane);
        ull a0 = umin64(key, m0); ull k1 = umax64(key, m0); m0 = a0;
        ull a1 = umin64(k1, m1);  ull k2 = umax64(k1, m1);  m1 = a1;
        ull a2 = umin64(k2, m2k); ull k3 = umax64(k2, m2k); m2k = a2;
        m3 = umin64(k3, m3);
    }

    // selection: 30x butterfly min over lane heads + pop (+ rare refill)
    int c = 0;
    ull mykey = 0;
    for (int sel = 0; sel < NK; sel++) {
        ull g = m0;
#pragma unroll
        for (int off = 32; off; off >>= 1) {
            ull o = __shfl_xor(g, off);
            g = o < g ? o : g;
        }
        if (m0 == g) {
            m0 = m1; m1 = m2k; m2k = m3; m3 = INF;
            c++;
            if (m0 == INF && c < 32) {
                // refill: rescan this lane's candidates > g
#pragma unroll
                for (int r = 0; r < 32; r++) {
                    unsigned hi = ((mflags >> r) & 1u) ? __float_as_uint(df[r]) : rmb;
                    ull key = ((ull)hi << 32) | (unsigned)(r*64 + lane);
                    if (key > g) {
                        ull a0 = umin64(key, m0); ull k1 = umax64(key, m0); m0 = a0;
                        ull a1 = umin64(k1, m1);  ull k2 = umax64(k1, m1);  m1 = a1;
                        ull a2 = umin64(k2, m2k); ull k3 = umax64(k2, m2k); m2k = a2;
                        m3 = umin64(k3, m3);
                    }
                }
            }
        }
        mykey = (lane == sel) ? g : mykey;
    }
    if (lane < NK) {
        int g = row * NK + lane;
        int j = (int)(mykey & 0xffffffffULL);
        dnb[g]    = __uint_as_float((unsigned)(mykey >> 32));
        eidx[g]   = j;
        eidx_f[g] = (float)j;
    }
}

// ------- kernel 2: features(fp8) + fp8 MFMA GEMM + LayerNorm, 512 thr / 8 waves -------
// fA[64][432] fp8: half the LDS bytes of f16 (27.6 KB -> 4-5 blocks/CU), and the
// 432B stride makes feature ds_write_b128 and A ds_read_b64 bank-uniform.
// Wave w: ALL 64 rows (mt=4), cols w*16..+15. B = 13 x 8-byte fp8 frags (26 VGPR).
__global__ __launch_bounds__(512, 8) void k_edge(const float4* __restrict__ atoms5,
                                              const int*   __restrict__ eidx,
                                              const float* __restrict__ dnb,
                                              const int*   __restrict__ ridx,
                                              const int*   __restrict__ chl,
                                              const float* __restrict__ posW,
                                              const float* __restrict__ posb,
                                              const unsigned char* __restrict__ Wt,
                                              const float* __restrict__ lns,
                                              const float* __restrict__ lno,
                                              float* __restrict__ Eout)
{
    __shared__ __align__(16) unsigned char fA[BM][FROW];   // 27648 B
    int t = threadIdx.x;
    int base = blockIdx.x * BM;

    int w    = t >> 6;
    int lane = t & 63;
    int l16  = lane & 15;
    int g8   = (lane >> 4) * 8;
    int ncol = w * 16;

    // ---- phase 1: features, p-split, fp8-packed.
    {
        int e = t >> 3;
        int q = t & 7;
        int g = base + e;
        int b = g / (NL * NK);
        int rem = g - b * (NL * NK);
        int i = rem / NK;
        int gi = b * NL + i;
        int j = eidx[g];
        int gj = b * NL + j;

        // pos features: thread q writes s = 2q, 2q+1 (2 fp8 bytes)
        int off = ridx[gi] - ridx[gj];
        int ec  = (chl[gi] == chl[gj]) ? 1 : 0;
        int dp  = min(max(off + 32, 0), 64);
        dp = ec ? dp : 65;
        {
            float p0 = posW[dp * 16 + 2*q]     + posb[2*q];
            float p1 = posW[dp * 16 + 2*q + 1] + posb[2*q + 1];
            int r = __builtin_amdgcn_cvt_pk_fp8_f32(p0, p1, 0, false);
            *(unsigned short*)&fA[e][q * 2] = (unsigned short)(r & 0xffff);
        }

        const float4* A4 = atoms5 + (size_t)gi * 5;
        const float4* B4 = atoms5 + (size_t)gj * 5;

        auto body = [&](int p) {
            float D;
            if (p == 0) {
                D = dnb[g];
            } else {
                float4 a  = A4[c_PA[p - 1]];
                float4 bb = B4[c_PB[p - 1]];
                float dx = a.x - bb.x, dy = a.y - bb.y, dz = a.z - bb.z;
                D = sqrtf(dx*dx + dy*dy + dz*dz + 1e-6f);
            }
            float tD = D * 0.8f;                  // prescale: z = tD - mu*0.8
            int wds[4];
#pragma unroll
            for (int gq = 0; gq < 4; gq++) {
                float v[4];
#pragma unroll
                for (int u = 0; u < 4; u++) {
                    int s = gq * 4 + u;
                    float z = tD - (1.6f + (float)s * 1.06666667f);
                    v[u] = __expf(-(z * z));
                }
                int r = __builtin_amdgcn_cvt_pk_fp8_f32(v[0], v[1], 0, false);
                r = __builtin_amdgcn_cvt_pk_fp8_f32(v[2], v[3], r, true);
                wds[gq] = r;
            }
            *(int4*)&fA[e][16 + p * 16] = make_int4(wds[0], wds[1], wds[2], wds[3]);
        };

#pragma unroll
        for (int pp = 0; pp < 3; pp++) body(q + pp * 8);
        if (q == 0) body(24);
    }

    // ---- B preload (fp8): 13 x 8B; issued before barrier, waits overlap it.
    const unsigned char* wtb = Wt + (size_t)(ncol + l16) * NEIN + g8;
    long bfr[13];
#pragma unroll
    for (int kt = 0; kt < 13; kt++)
        bfr[kt] = *(const long*)(wtb + kt * 32);

    __syncthreads();

    // ---- phase 2: GEMM. 52 MFMA + 52 ds_read_b64 per wave, zero global ops.
    f32x4 acc[4];
#pragma unroll
    for (int mt = 0; mt < 4; mt++) acc[mt] = (f32x4){0.f, 0.f, 0.f, 0.f};

#pragma unroll
    for (int kt = 0; kt < 13; kt++) {
#pragma unroll
        for (int mt = 0; mt < 4; mt++) {
            long a = *(const long*)(&fA[mt * 16 + l16][kt * 32 + g8]);
            acc[mt] = __builtin_amdgcn_mfma_f32_16x16x32_fp8_fp8(a, bfr[kt], acc[mt], 0, 0, 0);
        }
    }

    // ---- phase 3: LayerNorm. Reduce 16 cols in-wave, combine 8 waves via LDS.
    float sum[4][4], ssq[4][4];
#pragma unroll
    for (int mt = 0; mt < 4; mt++)
#pragma unroll
        for (int r = 0; r < 4; r++) {
            float v = acc[mt][r];
            sum[mt][r] = v;
            ssq[mt][r] = v * v;
        }
#pragma unroll
    for (int off = 1; off < 16; off <<= 1)
#pragma unroll
        for (int mt = 0; mt < 4; mt++)
#pragma unroll
            for (int r = 0; r < 4; r++) {
                sum[mt][r] += __shfl_xor(sum[mt][r], off);
                ssq[mt][r] += __shfl_xor(ssq[mt][r], off);
            }

    __syncthreads();                        // all fA reads done -> reuse as scratch
    float* red  = (float*)&fA[0][0];        // [64 rows][8 waves][2] = 4 KB
    float* red2 = red + 1024;               // [64 rows][2]
    if (l16 == 0) {
        int lg = lane >> 4;
#pragma unroll
        for (int mt = 0; mt < 4; mt++)
#pragma unroll
            for (int r = 0; r < 4; r++) {
                int row = mt * 16 + lg * 4 + r;
                red[(row * 8 + w) * 2 + 0] = sum[mt][r];
                red[(row * 8 + w) * 2 + 1] = ssq[mt][r];
            }
    }
    __syncthreads();
    if (t < 64) {
        float ts = 0.f, tq = 0.f;
#pragma unroll
        for (int u = 0; u < 8; u++) {
            ts += red[(t * 8 + u) * 2 + 0];
            tq += red[(t * 8 + u) * 2 + 1];
        }
        float mu  = ts * (1.0f / 128.0f);
        float var = tq * (1.0f / 128.0f) - mu * mu;
        red2[t * 2 + 0] = mu;
        red2[t * 2 + 1] = 1.0f / sqrtf(var + 1e-5f);
    }
    __syncthreads();

    float sc = lns[ncol + l16];
    float of = lno[ncol + l16];
    int lg = lane >> 4;
#pragma unroll
    for (int mt = 0; mt < 4; mt++)
#pragma unroll
        for (int r = 0; r < 4; r++) {
            int row = mt * 16 + lg * 4 + r;
            float mu = red2[row * 2 + 0];
            float rs = red2[row * 2 + 1];
            Eout[(size_t)(base + row) * NEF + ncol + l16] =
                sc * ((acc[mt][r] - mu) * rs) + of;
        }
}

extern "C" void kernel_launch(void* const* d_in, const int* in_sizes, int n_in,
                              void* d_out, int out_size, void* d_ws, size_t ws_size,
                              hipStream_t stream)
{
    const float* X    = (const float*)d_in[0];
    const float* mask = (const float*)d_in[1];
    const int*   ridx = (const int*)d_in[2];
    const int*   chl  = (const int*)d_in[3];
    const float* posW = (const float*)d_in[4];
    const float* posb = (const float*)d_in[5];
    const float* eW   = (const float*)d_in[6];
    const float* lns  = (const float*)d_in[7];
    const float* lno  = (const float*)d_in[8];

    float* Eout   = (float*)d_out;                                  // B*L*K*128
    float* eidx_f = Eout + (size_t)NB * NL * NK * NEF;              // B*L*K (as float)

    char* ws = (char*)d_ws;
    float4*        atoms5 = (float4*)ws;                            // 327680 B
    float*         dnb    = (float*)(ws + 327680);                  // 491520 B
    int*           eidx   = (int*)(ws + 819200);                    // 491520 B
    unsigned char* Wt     = (unsigned char*)(ws + 1310720);         // 53248 B
    float4*        caw4   = (float4*)(ws + 1363968);                // 65536 B

    k_atoms<<<(NB * NL + 255) / 256, 256, 0, stream>>>(X, mask, atoms5, caw4);
    k_wconv<<<(NEF * (NEIN/2) + 255) / 256, 256, 0, stream>>>(eW, Wt);
    k_topk<<<(NB * NL) / 4, 256, 0, stream>>>(caw4, dnb, eidx, eidx_f);
    k_edge<<<(NB * NL * NK) / BM, 512, 0, stream>>>(atoms5, eidx, dnb, ridx, chl,
                                                    posW, posb, Wt, lns, lno, Eout);
}

// Round 8
// 107.289 us; speedup vs baseline: 1.4583x; 1.0348x over previous
//
#include <hip/hip_runtime.h>
#include <math.h>

#define NB 2
#define NL 2048
#define NK 30
#define NEF 128
#define NEIN 416
#define BM 64            // edges per block in k_edge
#define FROW 432         // fA row stride (bytes): 16B-aligned, bank-uniform

typedef float f32x4 __attribute__((ext_vector_type(4)));
typedef unsigned long long ull;

__constant__ int c_PA[24] = {0,2,3,4,1,1,1,1,0,0,0,4,4,3,0,2,3,4,2,3,4,2,3,2};
__constant__ int c_PB[24] = {0,2,3,4,0,2,3,4,2,3,4,2,3,2,1,1,1,1,0,0,0,4,4,3};

__device__ inline ull umin64(ull a, ull b) { return a < b ? a : b; }
__device__ inline ull umax64(ull a, ull b) { return a > b ? a : b; }

// ---- kernel 0: atoms5 = [N,Ca,C,O,Cb] as 5x float4 per residue; caw4 = (Ca.xyz, mask)
__global__ void k_atoms(const float* __restrict__ X, const float* __restrict__ mask,
                        float4* __restrict__ atoms5, float4* __restrict__ caw4)
{
    int idx = blockIdx.x * blockDim.x + threadIdx.x;
    if (idx >= NB * NL) return;
    const float* x = X + (size_t)idx * 12;
    float N[3], Ca[3], C[3], O[3], bv[3], cv[3], av[3];
#pragma unroll
    for (int d = 0; d < 3; d++) { N[d] = x[d]; Ca[d] = x[3+d]; C[d] = x[6+d]; O[d] = x[9+d]; }
#pragma unroll
    for (int d = 0; d < 3; d++) { bv[d] = Ca[d] - N[d]; cv[d] = C[d] - Ca[d]; }
    av[0] = bv[1]*cv[2] - bv[2]*cv[1];
    av[1] = bv[2]*cv[0] - bv[0]*cv[2];
    av[2] = bv[0]*cv[1] - bv[1]*cv[0];
    float4* o = atoms5 + (size_t)idx * 5;
    o[0] = make_float4(N[0], N[1], N[2], 0.f);
    o[1] = make_float4(Ca[0], Ca[1], Ca[2], 0.f);
    o[2] = make_float4(C[0], C[1], C[2], 0.f);
    o[3] = make_float4(O[0], O[1], O[2], 0.f);
    float cb0 = -0.58273431f*av[0] + 0.56802827f*bv[0] - 0.54067466f*cv[0] + Ca[0];
    float cb1 = -0.58273431f*av[1] + 0.56802827f*bv[1] - 0.54067466f*cv[1] + Ca[1];
    float cb2 = -0.58273431f*av[2] + 0.56802827f*bv[2] - 0.54067466f*cv[2] + Ca[2];
    o[4] = make_float4(cb0, cb1, cb2, 0.f);
    caw4[idx] = make_float4(Ca[0], Ca[1], Ca[2], mask[idx]);
}

// ---- kernel 0b: W (416x128 f32) -> Wt (128x416 fp8 e4m3) ----
__global__ void k_wconv(const float* __restrict__ eW, unsigned char* __restrict__ Wt)
{
    int idx = blockIdx.x * blockDim.x + threadIdx.x;
    if (idx >= NEF * (NEIN / 2)) return;
    int c  = idx / (NEIN / 2);
    int k2 = idx - c * (NEIN / 2);
    float a = eW[(size_t)(2 * k2) * NEF + c];
    float b = eW[(size_t)(2 * k2 + 1) * NEF + c];
    int r = __builtin_amdgcn_cvt_pk_fp8_f32(a, b, 0, false);
    *(unsigned short*)&Wt[(size_t)c * NEIN + 2 * k2] = (unsigned short)(r & 0xffff);
}

// ---- kernel 1: exact top-30, one WAVE per row, streaming 4-slot min-list ----
__global__ __launch_bounds__(256, 8) void k_topk(const float4* __restrict__ caw4,
                                                 float* __restrict__ dnb,
                                                 int*   __restrict__ eidx,
                                                 float* __restrict__ eidx_f)
{
    __shared__ float4 ca[NL];
    int t = threadIdx.x;
    int base = blockIdx.x << 2;          // 4 rows per block (one per wave)
    int b = base >> 11;
    const float4* src = caw4 + (size_t)b * NL;
#pragma unroll
    for (int r = 0; r < NL/256; r++) ca[t + r*256] = src[t + r*256];
    __syncthreads();

    int w = t >> 6, lane = t & 63;
    int row = base + w;
    int i = row & (NL - 1);
    float4 ci = ca[i];
    float mi = ci.w;

    float df[32];
    unsigned mflags = 0;
    float lmax = 0.0f;
#pragma unroll
    for (int r = 0; r < 32; r++) {
        float4 cj = ca[r*64 + lane];
        float dx = __fsub_rn(ci.x, cj.x);
        float dy = __fsub_rn(ci.y, cj.y);
        float dz = __fsub_rn(ci.z, cj.z);
        float s  = __fadd_rn(__fadd_rn(__fmul_rn(dx,dx), __fmul_rn(dy,dy)), __fmul_rn(dz,dz));
        s = __fadd_rn(s, 1e-6f);
        float m2 = __fmul_rn(mi, cj.w);   // binary mask: 0 or 1
        float d  = __fmul_rn(m2, __fsqrt_rn(s));
        df[r] = d;
        lmax = fmaxf(lmax, d);
        mflags |= (m2 != 0.0f) ? (1u << r) : 0u;
    }
#pragma unroll
    for (int off = 32; off; off >>= 1) lmax = fmaxf(lmax, __shfl_xor(lmax, off));
    unsigned rmb = __float_as_uint(lmax);

    const ull INF = ~0ULL;
    ull m0 = INF, m1 = INF, m2k = INF, m3 = INF;
#pragma unroll
    for (int r = 0; r < 32; r++) {
        unsigned hi = ((mflags >> r) & 1u) ? __float_as_uint(df[r]) : rmb;
        ull key = ((ull)hi << 32) | (unsigned)(r*64 + lane);
        ull a0 = umin64(key, m0); ull k1 = umax64(key, m0); m0 = a0;
        ull a1 = umin64(k1, m1);  ull k2 = umax64(k1, m1);  m1 = a1;
        ull a2 = umin64(k2, m2k); ull k3 = umax64(k2, m2k); m2k = a2;
        m3 = umin64(k3, m3);
    }

    int c = 0;
    ull mykey = 0;
    for (int sel = 0; sel < NK; sel++) {
        ull g = m0;
#pragma unroll
        for (int off = 32; off; off >>= 1) {
            ull o = __shfl_xor(g, off);
            g = o < g ? o : g;
        }
        if (m0 == g) {
            m0 = m1; m1 = m2k; m2k = m3; m3 = INF;
            c++;
            if (m0 == INF && c < 32) {
#pragma unroll
                for (int r = 0; r < 32; r++) {
                    unsigned hi = ((mflags >> r) & 1u) ? __float_as_uint(df[r]) : rmb;
                    ull key = ((ull)hi << 32) | (unsigned)(r*64 + lane);
                    if (key > g) {
                        ull a0 = umin64(key, m0); ull k1 = umax64(key, m0); m0 = a0;
                        ull a1 = umin64(k1, m1);  ull k2 = umax64(k1, m1);  m1 = a1;
                        ull a2 = umin64(k2, m2k); ull k3 = umax64(k2, m2k); m2k = a2;
                        m3 = umin64(k3, m3);
                    }
                }
            }
        }
        mykey = (lane == sel) ? g : mykey;
    }
    if (lane < NK) {
        int g = row * NK + lane;
        int j = (int)(mykey & 0xffffffffULL);
        dnb[g]    = __uint_as_float((unsigned)(mykey >> 32));
        eidx[g]   = j;
        eidx_f[g] = (float)j;
    }
}

// ------- kernel 2: features(fp8) + fp8 MFMA GEMM + LayerNorm, 512 thr / 8 waves -------
// Epilogue stages normalized f32 rows in LDS (fA reuse) and streams them out as
// contiguous float4: 8 lanes = one full 128B line -> no read-for-ownership.
__global__ __launch_bounds__(512, 8) void k_edge(const float4* __restrict__ atoms5,
                                              const int*   __restrict__ eidx,
                                              const float* __restrict__ dnb,
                                              const int*   __restrict__ ridx,
                                              const int*   __restrict__ chl,
                                              const float* __restrict__ posW,
                                              const float* __restrict__ posb,
                                              const unsigned char* __restrict__ Wt,
                                              const float* __restrict__ lns,
                                              const float* __restrict__ lno,
                                              float* __restrict__ Eout)
{
    __shared__ __align__(16) unsigned char fA[BM][FROW];   // 27648 B
    int t = threadIdx.x;
    int base = blockIdx.x * BM;

    int w    = t >> 6;
    int lane = t & 63;
    int l16  = lane & 15;
    int g8   = (lane >> 4) * 8;
    int ncol = w * 16;

    // ---- phase 1: features, p-split, fp8-packed.
    {
        int e = t >> 3;
        int q = t & 7;
        int g = base + e;
        int b = g / (NL * NK);
        int rem = g - b * (NL * NK);
        int i = rem / NK;
        int gi = b * NL + i;
        int j = eidx[g];
        int gj = b * NL + j;

        int off = ridx[gi] - ridx[gj];
        int ec  = (chl[gi] == chl[gj]) ? 1 : 0;
        int dp  = min(max(off + 32, 0), 64);
        dp = ec ? dp : 65;
        {
            float p0 = posW[dp * 16 + 2*q]     + posb[2*q];
            float p1 = posW[dp * 16 + 2*q + 1] + posb[2*q + 1];
            int r = __builtin_amdgcn_cvt_pk_fp8_f32(p0, p1, 0, false);
            *(unsigned short*)&fA[e][q * 2] = (unsigned short)(r & 0xffff);
        }

        const float4* A4 = atoms5 + (size_t)gi * 5;
        const float4* B4 = atoms5 + (size_t)gj * 5;

        auto body = [&](int p) {
            float D;
            if (p == 0) {
                D = dnb[g];
            } else {
                float4 a  = A4[c_PA[p - 1]];
                float4 bb = B4[c_PB[p - 1]];
                float dx = a.x - bb.x, dy = a.y - bb.y, dz = a.z - bb.z;
                D = sqrtf(dx*dx + dy*dy + dz*dz + 1e-6f);
            }
            float tD = D * 0.8f;                  // prescale: z = tD - mu*0.8
            int wds[4];
#pragma unroll
            for (int gq = 0; gq < 4; gq++) {
                float v[4];
#pragma unroll
                for (int u = 0; u < 4; u++) {
                    int s = gq * 4 + u;
                    float z = tD - (1.6f + (float)s * 1.06666667f);
                    v[u] = __expf(-(z * z));
                }
                int r = __builtin_amdgcn_cvt_pk_fp8_f32(v[0], v[1], 0, false);
                r = __builtin_amdgcn_cvt_pk_fp8_f32(v[2], v[3], r, true);
                wds[gq] = r;
            }
            *(int4*)&fA[e][16 + p * 16] = make_int4(wds[0], wds[1], wds[2], wds[3]);
        };

#pragma unroll
        for (int pp = 0; pp < 3; pp++) body(q + pp * 8);
        if (q == 0) body(24);
    }

    // ---- B preload (fp8): 13 x 8B; issued before barrier, waits overlap it.
    const unsigned char* wtb = Wt + (size_t)(ncol + l16) * NEIN + g8;
    long bfr[13];
#pragma unroll
    for (int kt = 0; kt < 13; kt++)
        bfr[kt] = *(const long*)(wtb + kt * 32);

    __syncthreads();

    // ---- phase 2: GEMM. 52 MFMA + 52 ds_read_b64 per wave, zero global ops.
    f32x4 acc[4];
#pragma unroll
    for (int mt = 0; mt < 4; mt++) acc[mt] = (f32x4){0.f, 0.f, 0.f, 0.f};

#pragma unroll
    for (int kt = 0; kt < 13; kt++) {
#pragma unroll
        for (int mt = 0; mt < 4; mt++) {
            long a = *(const long*)(&fA[mt * 16 + l16][kt * 32 + g8]);
            acc[mt] = __builtin_amdgcn_mfma_f32_16x16x32_fp8_fp8(a, bfr[kt], acc[mt], 0, 0, 0);
        }
    }

    // ---- phase 3: LayerNorm stats. Reduce 16 cols in-wave, combine via LDS.
    float sum[4][4], ssq[4][4];
#pragma unroll
    for (int mt = 0; mt < 4; mt++)
#pragma unroll
        for (int r = 0; r < 4; r++) {
            float v = acc[mt][r];
            sum[mt][r] = v;
            ssq[mt][r] = v * v;
        }
#pragma unroll
    for (int off = 1; off < 16; off <<= 1)
#pragma unroll
        for (int mt = 0; mt < 4; mt++)
#pragma unroll
            for (int r = 0; r < 4; r++) {
                sum[mt][r] += __shfl_xor(sum[mt][r], off);
                ssq[mt][r] += __shfl_xor(ssq[mt][r], off);
            }

    __syncthreads();                        // all fA reads done -> reuse as scratch
    float* red     = (float*)&fA[0][0];     // [64 rows][8 waves][2] = 4 KB
    float* red2    = red + 1024;            // [64 rows][2] = 512 B
    float* staging = (float*)((char*)&fA[0][0] + 8192);  // 32 rows x 128 f32 = 16 KB
    if (l16 == 0) {
        int lg = lane >> 4;
#pragma unroll
        for (int mt = 0; mt < 4; mt++)
#pragma unroll
            for (int r = 0; r < 4; r++) {
                int row = mt * 16 + lg * 4 + r;
                red[(row * 8 + w) * 2 + 0] = sum[mt][r];
                red[(row * 8 + w) * 2 + 1] = ssq[mt][r];
            }
    }
    __syncthreads();
    if (t < 64) {
        float ts = 0.f, tq = 0.f;
#pragma unroll
        for (int u = 0; u < 8; u++) {
            ts += red[(t * 8 + u) * 2 + 0];
            tq += red[(t * 8 + u) * 2 + 1];
        }
        float mu  = ts * (1.0f / 128.0f);
        float var = tq * (1.0f / 128.0f) - mu * mu;
        red2[t * 2 + 0] = mu;
        red2[t * 2 + 1] = 1.0f / sqrtf(var + 1e-5f);
    }
    __syncthreads();

    // ---- phase 4: normalized epilogue via LDS staging, full-line stores.
    float sc = lns[ncol + l16];
    float of = lno[ncol + l16];
    int lg = lane >> 6 ? 0 : (lane >> 4);   // lg = lane>>4 (kept simple below)
    lg = lane >> 4;
    float4* Eout4 = (float4*)Eout;
#pragma unroll
    for (int h = 0; h < 2; h++) {
        // stage rows 32h..32h+31 (mt = 2h, 2h+1)
#pragma unroll
        for (int m2 = 0; m2 < 2; m2++) {
            int mt = 2 * h + m2;
#pragma unroll
            for (int r = 0; r < 4; r++) {
                int row  = mt * 16 + lg * 4 + r;      // global row in tile
                int lrow = row - 32 * h;              // 0..31
                float mu = red2[row * 2 + 0];
                float rs = red2[row * 2 + 1];
                staging[lrow * 128 + ncol + l16] =
                    sc * ((acc[mt][r] - mu) * rs) + of;
            }
        }
        __syncthreads();
        // stream out: 1024 float4 = 32 rows x 512B, consecutive threads -> consecutive 16B
#pragma unroll
        for (int u = 0; u < 2; u++) {
            int idx  = u * 512 + t;                   // 0..1023
            int lrow = idx >> 5;
            int c4   = idx & 31;
            Eout4[(size_t)(base + 32 * h + lrow) * 32 + c4] =
                *(float4*)&staging[lrow * 128 + c4 * 4];
        }
        __syncthreads();
    }
}

extern "C" void kernel_launch(void* const* d_in, const int* in_sizes, int n_in,
                              void* d_out, int out_size, void* d_ws, size_t ws_size,
                              hipStream_t stream)
{
    const float* X    = (const float*)d_in[0];
    const float* mask = (const float*)d_in[1];
    const int*   ridx = (const int*)d_in[2];
    const int*   chl  = (const int*)d_in[3];
    const float* posW = (const float*)d_in[4];
    const float* posb = (const float*)d_in[5];
    const float* eW   = (const float*)d_in[6];
    const float* lns  = (const float*)d_in[7];
    const float* lno  = (const float*)d_in[8];

    float* Eout   = (float*)d_out;                                  // B*L*K*128
    float* eidx_f = Eout + (size_t)NB * NL * NK * NEF;              // B*L*K (as float)

    char* ws = (char*)d_ws;
    float4*        atoms5 = (float4*)ws;                            // 327680 B
    float*         dnb    = (float*)(ws + 327680);                  // 491520 B
    int*           eidx   = (int*)(ws + 819200);                    // 491520 B
    unsigned char* Wt     = (unsigned char*)(ws + 1310720);         // 53248 B
    float4*        caw4   = (float4*)(ws + 1363968);                // 65536 B

    k_atoms<<<(NB * NL + 255) / 256, 256, 0, stream>>>(X, mask, atoms5, caw4);
    k_wconv<<<(NEF * (NEIN/2) + 255) / 256, 256, 0, stream>>>(eW, Wt);
    k_topk<<<(NB * NL) / 4, 256, 0, stream>>>(caw4, dnb, eidx, eidx_f);
    k_edge<<<(NB * NL * NK) / BM, 512, 0, stream>>>(atoms5, eidx, dnb, ridx, chl,
                                                    posW, posb, Wt, lns, lno, Eout);
}

// Round 10
// 106.646 us; speedup vs baseline: 1.4671x; 1.0060x over previous
//
#include <hip/hip_runtime.h>
#include <math.h>

#define NB 2
#define NL 2048
#define NK 30
#define NEF 128
#define NEIN 416
#define BM 64            // edges per block in k_edge
#define FROW 432         // fA row stride (bytes): 16B-aligned, bank-uniform

typedef float f32x4 __attribute__((ext_vector_type(4)));
typedef unsigned long long ull;

__constant__ int c_PA[24] = {0,2,3,4,1,1,1,1,0,0,0,4,4,3,0,2,3,4,2,3,4,2,3,2};
__constant__ int c_PB[24] = {0,2,3,4,0,2,3,4,2,3,4,2,3,2,1,1,1,1,0,0,0,4,4,3};

__device__ inline ull umin64(ull a, ull b) { return a < b ? a : b; }
__device__ inline ull umax64(ull a, ull b) { return a > b ? a : b; }

// ---- kernel 0: atoms5 = [N,Ca,C,O,Cb] as 5x float4 per residue; caw4 = (Ca.xyz, mask)
__global__ void k_atoms(const float* __restrict__ X, const float* __restrict__ mask,
                        float4* __restrict__ atoms5, float4* __restrict__ caw4)
{
    int idx = blockIdx.x * blockDim.x + threadIdx.x;
    if (idx >= NB * NL) return;
    const float* x = X + (size_t)idx * 12;
    float N[3], Ca[3], C[3], O[3], bv[3], cv[3], av[3];
#pragma unroll
    for (int d = 0; d < 3; d++) { N[d] = x[d]; Ca[d] = x[3+d]; C[d] = x[6+d]; O[d] = x[9+d]; }
#pragma unroll
    for (int d = 0; d < 3; d++) { bv[d] = Ca[d] - N[d]; cv[d] = C[d] - Ca[d]; }
    av[0] = bv[1]*cv[2] - bv[2]*cv[1];
    av[1] = bv[2]*cv[0] - bv[0]*cv[2];
    av[2] = bv[0]*cv[1] - bv[1]*cv[0];
    float4* o = atoms5 + (size_t)idx * 5;
    o[0] = make_float4(N[0], N[1], N[2], 0.f);
    o[1] = make_float4(Ca[0], Ca[1], Ca[2], 0.f);
    o[2] = make_float4(C[0], C[1], C[2], 0.f);
    o[3] = make_float4(O[0], O[1], O[2], 0.f);
    float cb0 = -0.58273431f*av[0] + 0.56802827f*bv[0] - 0.54067466f*cv[0] + Ca[0];
    float cb1 = -0.58273431f*av[1] + 0.56802827f*bv[1] - 0.54067466f*cv[1] + Ca[1];
    float cb2 = -0.58273431f*av[2] + 0.56802827f*bv[2] - 0.54067466f*cv[2] + Ca[2];
    o[4] = make_float4(cb0, cb1, cb2, 0.f);
    caw4[idx] = make_float4(Ca[0], Ca[1], Ca[2], mask[idx]);
}

// ---- kernel 0b: W (416x128 f32) -> Wt (128x416 fp8 e4m3) ----
__global__ void k_wconv(const float* __restrict__ eW, unsigned char* __restrict__ Wt)
{
    int idx = blockIdx.x * blockDim.x + threadIdx.x;
    if (idx >= NEF * (NEIN / 2)) return;
    int c  = idx / (NEIN / 2);
    int k2 = idx - c * (NEIN / 2);
    float a = eW[(size_t)(2 * k2) * NEF + c];
    float b = eW[(size_t)(2 * k2 + 1) * NEF + c];
    int r = __builtin_amdgcn_cvt_pk_fp8_f32(a, b, 0, false);
    *(unsigned short*)&Wt[(size_t)c * NEIN + 2 * k2] = (unsigned short)(r & 0xffff);
}

// ---- kernel 1: exact top-30, one WAVE per row, streaming 4-slot min-list ----
__global__ __launch_bounds__(256, 8) void k_topk(const float4* __restrict__ caw4,
                                                 float* __restrict__ dnb,
                                                 int*   __restrict__ eidx,
                                                 float* __restrict__ eidx_f)
{
    __shared__ float4 ca[NL];
    int t = threadIdx.x;
    int base = blockIdx.x << 2;          // 4 rows per block (one per wave)
    int b = base >> 11;
    const float4* src = caw4 + (size_t)b * NL;
#pragma unroll
    for (int r = 0; r < NL/256; r++) ca[t + r*256] = src[t + r*256];
    __syncthreads();

    int w = t >> 6, lane = t & 63;
    int row = base + w;
    int i = row & (NL - 1);
    float4 ci = ca[i];
    float mi = ci.w;

    float df[32];
    unsigned mflags = 0;
    float lmax = 0.0f;
#pragma unroll
    for (int r = 0; r < 32; r++) {
        float4 cj = ca[r*64 + lane];
        float dx = __fsub_rn(ci.x, cj.x);
        float dy = __fsub_rn(ci.y, cj.y);
        float dz = __fsub_rn(ci.z, cj.z);
        float s  = __fadd_rn(__fadd_rn(__fmul_rn(dx,dx), __fmul_rn(dy,dy)), __fmul_rn(dz,dz));
        s = __fadd_rn(s, 1e-6f);
        float m2 = __fmul_rn(mi, cj.w);   // binary mask: 0 or 1
        float d  = __fmul_rn(m2, __fsqrt_rn(s));
        df[r] = d;
        lmax = fmaxf(lmax, d);
        mflags |= (m2 != 0.0f) ? (1u << r) : 0u;
    }
#pragma unroll
    for (int off = 32; off; off >>= 1) lmax = fmaxf(lmax, __shfl_xor(lmax, off));
    unsigned rmb = __float_as_uint(lmax);

    const ull INF = ~0ULL;
    ull m0 = INF, m1 = INF, m2k = INF, m3 = INF;
#pragma unroll
    for (int r = 0; r < 32; r++) {
        unsigned hi = ((mflags >> r) & 1u) ? __float_as_uint(df[r]) : rmb;
        ull key = ((ull)hi << 32) | (unsigned)(r*64 + lane);
        ull a0 = umin64(key, m0); ull k1 = umax64(key, m0); m0 = a0;
        ull a1 = umin64(k1, m1);  ull k2 = umax64(k1, m1);  m1 = a1;
        ull a2 = umin64(k2, m2k); ull k3 = umax64(k2, m2k); m2k = a2;
        m3 = umin64(k3, m3);
    }

    int c = 0;
    ull mykey = 0;
    for (int sel = 0; sel < NK; sel++) {
        ull g = m0;
#pragma unroll
        for (int off = 32; off; off >>= 1) {
            ull o = __shfl_xor(g, off);
            g = o < g ? o : g;
        }
        if (m0 == g) {
            m0 = m1; m1 = m2k; m2k = m3; m3 = INF;
            c++;
            if (m0 == INF && c < 32) {
#pragma unroll
                for (int r = 0; r < 32; r++) {
                    unsigned hi = ((mflags >> r) & 1u) ? __float_as_uint(df[r]) : rmb;
                    ull key = ((ull)hi << 32) | (unsigned)(r*64 + lane);
                    if (key > g) {
                        ull a0 = umin64(key, m0); ull k1 = umax64(key, m0); m0 = a0;
                        ull a1 = umin64(k1, m1);  ull k2 = umax64(k1, m1);  m1 = a1;
                        ull a2 = umin64(k2, m2k); ull k3 = umax64(k2, m2k); m2k = a2;
                        m3 = umin64(k3, m3);
                    }
                }
            }
        }
        mykey = (lane == sel) ? g : mykey;
    }
    if (lane < NK) {
        int g = row * NK + lane;
        int j = (int)(mykey & 0xffffffffULL);
        dnb[g]    = __uint_as_float((unsigned)(mykey >> 32));
        eidx[g]   = j;
        eidx_f[g] = (float)j;
    }
}

// ------- kernel 2: features(fp8) + fp8 MFMA GEMM + LayerNorm, 512 thr / 8 waves -------
// Epilogue: LDS-staged rows streamed out with NON-TEMPORAL f32x4 stores (no L2
// write-allocate -> no RFO thrash, Wt stays L2-resident).
__global__ __launch_bounds__(512, 8) void k_edge(const float4* __restrict__ atoms5,
                                              const int*   __restrict__ eidx,
                                              const float* __restrict__ dnb,
                                              const int*   __restrict__ ridx,
                                              const int*   __restrict__ chl,
                                              const float* __restrict__ posW,
                                              const float* __restrict__ posb,
                                              const unsigned char* __restrict__ Wt,
                                              const float* __restrict__ lns,
                                              const float* __restrict__ lno,
                                              float* __restrict__ Eout)
{
    __shared__ __align__(16) unsigned char fA[BM][FROW];   // 27648 B
    int t = threadIdx.x;
    int base = blockIdx.x * BM;

    int w    = t >> 6;
    int lane = t & 63;
    int l16  = lane & 15;
    int g8   = (lane >> 4) * 8;
    int ncol = w * 16;

    // ---- phase 1: features, p-split, fp8-packed.
    {
        int e = t >> 3;
        int q = t & 7;
        int g = base + e;
        int b = g / (NL * NK);
        int rem = g - b * (NL * NK);
        int i = rem / NK;
        int gi = b * NL + i;
        int j = eidx[g];
        int gj = b * NL + j;

        int off = ridx[gi] - ridx[gj];
        int ec  = (chl[gi] == chl[gj]) ? 1 : 0;
        int dp  = min(max(off + 32, 0), 64);
        dp = ec ? dp : 65;
        {
            float p0 = posW[dp * 16 + 2*q]     + posb[2*q];
            float p1 = posW[dp * 16 + 2*q + 1] + posb[2*q + 1];
            int r = __builtin_amdgcn_cvt_pk_fp8_f32(p0, p1, 0, false);
            *(unsigned short*)&fA[e][q * 2] = (unsigned short)(r & 0xffff);
        }

        const float4* A4 = atoms5 + (size_t)gi * 5;
        const float4* B4 = atoms5 + (size_t)gj * 5;

        auto body = [&](int p) {
            float D;
            if (p == 0) {
                D = dnb[g];
            } else {
                float4 a  = A4[c_PA[p - 1]];
                float4 bb = B4[c_PB[p - 1]];
                float dx = a.x - bb.x, dy = a.y - bb.y, dz = a.z - bb.z;
                D = sqrtf(dx*dx + dy*dy + dz*dz + 1e-6f);
            }
            float tD = D * 0.8f;                  // prescale: z = tD - mu*0.8
            int wds[4];
#pragma unroll
            for (int gq = 0; gq < 4; gq++) {
                float v[4];
#pragma unroll
                for (int u = 0; u < 4; u++) {
                    int s = gq * 4 + u;
                    float z = tD - (1.6f + (float)s * 1.06666667f);
                    v[u] = __expf(-(z * z));
                }
                int r = __builtin_amdgcn_cvt_pk_fp8_f32(v[0], v[1], 0, false);
                r = __builtin_amdgcn_cvt_pk_fp8_f32(v[2], v[3], r, true);
                wds[gq] = r;
            }
            *(int4*)&fA[e][16 + p * 16] = make_int4(wds[0], wds[1], wds[2], wds[3]);
        };

#pragma unroll
        for (int pp = 0; pp < 3; pp++) body(q + pp * 8);
        if (q == 0) body(24);
    }

    // ---- B preload (fp8): 13 x 8B; issued before barrier, waits overlap it.
    const unsigned char* wtb = Wt + (size_t)(ncol + l16) * NEIN + g8;
    long bfr[13];
#pragma unroll
    for (int kt = 0; kt < 13; kt++)
        bfr[kt] = *(const long*)(wtb + kt * 32);

    __syncthreads();

    // ---- phase 2: GEMM. 52 MFMA + 52 ds_read_b64 per wave, zero global ops.
    f32x4 acc[4];
#pragma unroll
    for (int mt = 0; mt < 4; mt++) acc[mt] = (f32x4){0.f, 0.f, 0.f, 0.f};

#pragma unroll
    for (int kt = 0; kt < 13; kt++) {
#pragma unroll
        for (int mt = 0; mt < 4; mt++) {
            long a = *(const long*)(&fA[mt * 16 + l16][kt * 32 + g8]);
            acc[mt] = __builtin_amdgcn_mfma_f32_16x16x32_fp8_fp8(a, bfr[kt], acc[mt], 0, 0, 0);
        }
    }

    // ---- phase 3: LayerNorm stats. Reduce 16 cols in-wave, combine via LDS.
    float sum[4][4], ssq[4][4];
#pragma unroll
    for (int mt = 0; mt < 4; mt++)
#pragma unroll
        for (int r = 0; r < 4; r++) {
            float v = acc[mt][r];
            sum[mt][r] = v;
            ssq[mt][r] = v * v;
        }
#pragma unroll
    for (int off = 1; off < 16; off <<= 1)
#pragma unroll
        for (int mt = 0; mt < 4; mt++)
#pragma unroll
            for (int r = 0; r < 4; r++) {
                sum[mt][r] += __shfl_xor(sum[mt][r], off);
                ssq[mt][r] += __shfl_xor(ssq[mt][r], off);
            }

    __syncthreads();                        // all fA reads done -> reuse as scratch
    float* red     = (float*)&fA[0][0];     // [64 rows][8 waves][2] = 4 KB
    float* red2    = red + 1024;            // [64 rows][2] = 512 B
    float* staging = (float*)((char*)&fA[0][0] + 8192);  // 32 rows x 128 f32 = 16 KB
    int lg = lane >> 4;
    if (l16 == 0) {
#pragma unroll
        for (int mt = 0; mt < 4; mt++)
#pragma unroll
            for (int r = 0; r < 4; r++) {
                int row = mt * 16 + lg * 4 + r;
                red[(row * 8 + w) * 2 + 0] = sum[mt][r];
                red[(row * 8 + w) * 2 + 1] = ssq[mt][r];
            }
    }
    __syncthreads();
    if (t < 64) {
        float ts = 0.f, tq = 0.f;
#pragma unroll
        for (int u = 0; u < 8; u++) {
            ts += red[(t * 8 + u) * 2 + 0];
            tq += red[(t * 8 + u) * 2 + 1];
        }
        float mu  = ts * (1.0f / 128.0f);
        float var = tq * (1.0f / 128.0f) - mu * mu;
        red2[t * 2 + 0] = mu;
        red2[t * 2 + 1] = 1.0f / sqrtf(var + 1e-5f);
    }
    __syncthreads();

    // ---- phase 4: normalized epilogue via LDS staging, non-temporal full-line stores.
    float sc = lns[ncol + l16];
    float of = lno[ncol + l16];
    f32x4* Eout4 = (f32x4*)Eout;
#pragma unroll
    for (int h = 0; h < 2; h++) {
#pragma unroll
        for (int m2 = 0; m2 < 2; m2++) {
            int mt = 2 * h + m2;
#pragma unroll
            for (int r = 0; r < 4; r++) {
                int row  = mt * 16 + lg * 4 + r;      // global row in tile
                int lrow = row - 32 * h;              // 0..31
                float mu = red2[row * 2 + 0];
                float rs = red2[row * 2 + 1];
                staging[lrow * 128 + ncol + l16] =
                    sc * ((acc[mt][r] - mu) * rs) + of;
            }
        }
        __syncthreads();
        // stream out: 1024 f32x4 = 32 rows x 512B, consecutive threads -> consecutive 16B
#pragma unroll
        for (int u = 0; u < 2; u++) {
            int idx  = u * 512 + t;                   // 0..1023
            int lrow = idx >> 5;
            int c4   = idx & 31;
            f32x4 v = *(f32x4*)&staging[lrow * 128 + c4 * 4];
            __builtin_nontemporal_store(v, &Eout4[(size_t)(base + 32 * h + lrow) * 32 + c4]);
        }
        __syncthreads();
    }
}

extern "C" void kernel_launch(void* const* d_in, const int* in_sizes, int n_in,
                              void* d_out, int out_size, void* d_ws, size_t ws_size,
                              hipStream_t stream)
{
    const float* X    = (const float*)d_in[0];
    const float* mask = (const float*)d_in[1];
    const int*   ridx = (const int*)d_in[2];
    const int*   chl  = (const int*)d_in[3];
    const float* posW = (const float*)d_in[4];
    const float* posb = (const float*)d_in[5];
    const float* eW   = (const float*)d_in[6];
    const float* lns  = (const float*)d_in[7];
    const float* lno  = (const float*)d_in[8];

    float* Eout   = (float*)d_out;                                  // B*L*K*128
    float* eidx_f = Eout + (size_t)NB * NL * NK * NEF;              // B*L*K (as float)

    char* ws = (char*)d_ws;
    float4*        atoms5 = (float4*)ws;                            // 327680 B
    float*         dnb    = (float*)(ws + 327680);                  // 491520 B
    int*           eidx   = (int*)(ws + 819200);                    // 491520 B
    unsigned char* Wt     = (unsigned char*)(ws + 1310720);         // 53248 B
    float4*        caw4   = (float4*)(ws + 1363968);                // 65536 B

    k_atoms<<<(NB * NL + 255) / 256, 256, 0, stream>>>(X, mask, atoms5, caw4);
    k_wconv<<<(NEF * (NEIN/2) + 255) / 256, 256, 0, stream>>>(eW, Wt);
    k_topk<<<(NB * NL) / 4, 256, 0, stream>>>(caw4, dnb, eidx, eidx_f);
    k_edge<<<(NB * NL * NK) / BM, 512, 0, stream>>>(atoms5, eidx, dnb, ridx, chl,
                                                    posW, posb, Wt, lns, lno, Eout);
}

// Round 11
// 97.883 us; speedup vs baseline: 1.5985x; 1.0895x over previous
//
#include <hip/hip_runtime.h>
#include <math.h>

#define NB 2
#define NL 2048
#define NK 30
#define NEF 128
#define NEIN 416
#define BM 64            // edges per block in k_edge
#define FROW 432         // fA row stride (bytes): 16B-aligned, bank-uniform

typedef float f32x4 __attribute__((ext_vector_type(4)));
typedef unsigned long long ull;

__constant__ int c_PA[24] = {0,2,3,4,1,1,1,1,0,0,0,4,4,3,0,2,3,4,2,3,4,2,3,2};
__constant__ int c_PB[24] = {0,2,3,4,0,2,3,4,2,3,4,2,3,2,1,1,1,1,0,0,0,4,4,3};

__device__ inline ull umin64(ull a, ull b) { return a < b ? a : b; }
__device__ inline ull umax64(ull a, ull b) { return a > b ? a : b; }

// ---- kernel 0: atoms5 = [N,Ca,C,O,Cb] as 5x float4 per residue; caw4 = (Ca.xyz, mask)
__global__ void k_atoms(const float* __restrict__ X, const float* __restrict__ mask,
                        float4* __restrict__ atoms5, float4* __restrict__ caw4)
{
    int idx = blockIdx.x * blockDim.x + threadIdx.x;
    if (idx >= NB * NL) return;
    const float* x = X + (size_t)idx * 12;
    float N[3], Ca[3], C[3], O[3], bv[3], cv[3], av[3];
#pragma unroll
    for (int d = 0; d < 3; d++) { N[d] = x[d]; Ca[d] = x[3+d]; C[d] = x[6+d]; O[d] = x[9+d]; }
#pragma unroll
    for (int d = 0; d < 3; d++) { bv[d] = Ca[d] - N[d]; cv[d] = C[d] - Ca[d]; }
    av[0] = bv[1]*cv[2] - bv[2]*cv[1];
    av[1] = bv[2]*cv[0] - bv[0]*cv[2];
    av[2] = bv[0]*cv[1] - bv[1]*cv[0];
    float4* o = atoms5 + (size_t)idx * 5;
    o[0] = make_float4(N[0], N[1], N[2], 0.f);
    o[1] = make_float4(Ca[0], Ca[1], Ca[2], 0.f);
    o[2] = make_float4(C[0], C[1], C[2], 0.f);
    o[3] = make_float4(O[0], O[1], O[2], 0.f);
    float cb0 = -0.58273431f*av[0] + 0.56802827f*bv[0] - 0.54067466f*cv[0] + Ca[0];
    float cb1 = -0.58273431f*av[1] + 0.56802827f*bv[1] - 0.54067466f*cv[1] + Ca[1];
    float cb2 = -0.58273431f*av[2] + 0.56802827f*bv[2] - 0.54067466f*cv[2] + Ca[2];
    o[4] = make_float4(cb0, cb1, cb2, 0.f);
    caw4[idx] = make_float4(Ca[0], Ca[1], Ca[2], mask[idx]);
}

// ---- kernel 0b: W (416x128 f32) -> Wt (128x416 fp8 e4m3) ----
__global__ void k_wconv(const float* __restrict__ eW, unsigned char* __restrict__ Wt)
{
    int idx = blockIdx.x * blockDim.x + threadIdx.x;
    if (idx >= NEF * (NEIN / 2)) return;
    int c  = idx / (NEIN / 2);
    int k2 = idx - c * (NEIN / 2);
    float a = eW[(size_t)(2 * k2) * NEF + c];
    float b = eW[(size_t)(2 * k2 + 1) * NEF + c];
    int r = __builtin_amdgcn_cvt_pk_fp8_f32(a, b, 0, false);
    *(unsigned short*)&Wt[(size_t)c * NEIN + 2 * k2] = (unsigned short)(r & 0xffff);
}

// ---- kernel 1: exact top-30, one WAVE per row, streaming 4-slot min-list ----
__global__ __launch_bounds__(256, 4) void k_topk(const float4* __restrict__ caw4,
                                                 float* __restrict__ dnb,
                                                 int*   __restrict__ eidx,
                                                 float* __restrict__ eidx_f)
{
    __shared__ float4 ca[NL];
    int t = threadIdx.x;
    int base = blockIdx.x << 2;          // 4 rows per block (one per wave)
    int b = base >> 11;
    const float4* src = caw4 + (size_t)b * NL;
#pragma unroll
    for (int r = 0; r < NL/256; r++) ca[t + r*256] = src[t + r*256];
    __syncthreads();

    int w = t >> 6, lane = t & 63;
    int row = base + w;
    int i = row & (NL - 1);
    float4 ci = ca[i];
    float mi = ci.w;

    float df[32];
    unsigned mflags = 0;
    float lmax = 0.0f;
#pragma unroll
    for (int r = 0; r < 32; r++) {
        float4 cj = ca[r*64 + lane];
        float dx = __fsub_rn(ci.x, cj.x);
        float dy = __fsub_rn(ci.y, cj.y);
        float dz = __fsub_rn(ci.z, cj.z);
        float s  = __fadd_rn(__fadd_rn(__fmul_rn(dx,dx), __fmul_rn(dy,dy)), __fmul_rn(dz,dz));
        s = __fadd_rn(s, 1e-6f);
        float m2 = __fmul_rn(mi, cj.w);   // binary mask: 0 or 1
        float d  = __fmul_rn(m2, __fsqrt_rn(s));
        df[r] = d;
        lmax = fmaxf(lmax, d);
        mflags |= (m2 != 0.0f) ? (1u << r) : 0u;
    }
#pragma unroll
    for (int off = 32; off; off >>= 1) lmax = fmaxf(lmax, __shfl_xor(lmax, off));
    unsigned rmb = __float_as_uint(lmax);

    const ull INF = ~0ULL;
    ull m0 = INF, m1 = INF, m2k = INF, m3 = INF;
#pragma unroll
    for (int r = 0; r < 32; r++) {
        unsigned hi = ((mflags >> r) & 1u) ? __float_as_uint(df[r]) : rmb;
        ull key = ((ull)hi << 32) | (unsigned)(r*64 + lane);
        ull a0 = umin64(key, m0); ull k1 = umax64(key, m0); m0 = a0;
        ull a1 = umin64(k1, m1);  ull k2 = umax64(k1, m1);  m1 = a1;
        ull a2 = umin64(k2, m2k); ull k3 = umax64(k2, m2k); m2k = a2;
        m3 = umin64(k3, m3);
    }

    int c = 0;
    ull mykey = 0;
    for (int sel = 0; sel < NK; sel++) {
        ull g = m0;
#pragma unroll
        for (int off = 32; off; off >>= 1) {
            ull o = __shfl_xor(g, off);
            g = o < g ? o : g;
        }
        if (m0 == g) {
            m0 = m1; m1 = m2k; m2k = m3; m3 = INF;
            c++;
            if (m0 == INF && c < 32) {
#pragma unroll
                for (int r = 0; r < 32; r++) {
                    unsigned hi = ((mflags >> r) & 1u) ? __float_as_uint(df[r]) : rmb;
                    ull key = ((ull)hi << 32) | (unsigned)(r*64 + lane);
                    if (key > g) {
                        ull a0 = umin64(key, m0); ull k1 = umax64(key, m0); m0 = a0;
                        ull a1 = umin64(k1, m1);  ull k2 = umax64(k1, m1);  m1 = a1;
                        ull a2 = umin64(k2, m2k); ull k3 = umax64(k2, m2k); m2k = a2;
                        m3 = umin64(k3, m3);
                    }
                }
            }
        }
        mykey = (lane == sel) ? g : mykey;
    }
    if (lane < NK) {
        int g = row * NK + lane;
        int j = (int)(mykey & 0xffffffffULL);
        dnb[g]    = __uint_as_float((unsigned)(mykey >> 32));
        eidx[g]   = j;
        eidx_f[g] = (float)j;
    }
}

// ------- kernel 2: features(fp8) + fp8 MFMA GEMM + LayerNorm, 512 thr / 8 waves -------
// __launch_bounds__(512,4): 128-VGPR cap. (512,8) capped at 64 and spilled
// bfr/acc/sum to scratch -> ~160MB of global scratch traffic (r7-r10 FETCH/WRITE).
__global__ __launch_bounds__(512, 4) void k_edge(const float4* __restrict__ atoms5,
                                              const int*   __restrict__ eidx,
                                              const float* __restrict__ dnb,
                                              const int*   __restrict__ ridx,
                                              const int*   __restrict__ chl,
                                              const float* __restrict__ posW,
                                              const float* __restrict__ posb,
                                              const unsigned char* __restrict__ Wt,
                                              const float* __restrict__ lns,
                                              const float* __restrict__ lno,
                                              float* __restrict__ Eout)
{
    __shared__ __align__(16) unsigned char fA[BM][FROW];   // 27648 B
    int t = threadIdx.x;
    int base = blockIdx.x * BM;

    int w    = t >> 6;
    int lane = t & 63;
    int l16  = lane & 15;
    int g8   = (lane >> 4) * 8;
    int ncol = w * 16;

    // ---- phase 1: features, p-split, fp8-packed.
    {
        int e = t >> 3;
        int q = t & 7;
        int g = base + e;
        int b = g / (NL * NK);
        int rem = g - b * (NL * NK);
        int i = rem / NK;
        int gi = b * NL + i;
        int j = eidx[g];
        int gj = b * NL + j;

        int off = ridx[gi] - ridx[gj];
        int ec  = (chl[gi] == chl[gj]) ? 1 : 0;
        int dp  = min(max(off + 32, 0), 64);
        dp = ec ? dp : 65;
        {
            float p0 = posW[dp * 16 + 2*q]     + posb[2*q];
            float p1 = posW[dp * 16 + 2*q + 1] + posb[2*q + 1];
            int r = __builtin_amdgcn_cvt_pk_fp8_f32(p0, p1, 0, false);
            *(unsigned short*)&fA[e][q * 2] = (unsigned short)(r & 0xffff);
        }

        const float4* A4 = atoms5 + (size_t)gi * 5;
        const float4* B4 = atoms5 + (size_t)gj * 5;

        auto body = [&](int p) {
            float D;
            if (p == 0) {
                D = dnb[g];
            } else {
                float4 a  = A4[c_PA[p - 1]];
                float4 bb = B4[c_PB[p - 1]];
                float dx = a.x - bb.x, dy = a.y - bb.y, dz = a.z - bb.z;
                D = sqrtf(dx*dx + dy*dy + dz*dz + 1e-6f);
            }
            float tD = D * 0.8f;                  // prescale: z = tD - mu*0.8
            int wds[4];
#pragma unroll
            for (int gq = 0; gq < 4; gq++) {
                float v[4];
#pragma unroll
                for (int u = 0; u < 4; u++) {
                    int s = gq * 4 + u;
                    float z = tD - (1.6f + (float)s * 1.06666667f);
                    v[u] = __expf(-(z * z));
                }
                int r = __builtin_amdgcn_cvt_pk_fp8_f32(v[0], v[1], 0, false);
                r = __builtin_amdgcn_cvt_pk_fp8_f32(v[2], v[3], r, true);
                wds[gq] = r;
            }
            *(int4*)&fA[e][16 + p * 16] = make_int4(wds[0], wds[1], wds[2], wds[3]);
        };

#pragma unroll
        for (int pp = 0; pp < 3; pp++) body(q + pp * 8);
        if (q == 0) body(24);
    }

    // ---- B preload (fp8): 13 x 8B; issued before barrier, waits overlap it.
    const unsigned char* wtb = Wt + (size_t)(ncol + l16) * NEIN + g8;
    long bfr[13];
#pragma unroll
    for (int kt = 0; kt < 13; kt++)
        bfr[kt] = *(const long*)(wtb + kt * 32);

    __syncthreads();

    // ---- phase 2: GEMM. 52 MFMA + 52 ds_read_b64 per wave, zero global ops.
    f32x4 acc[4];
#pragma unroll
    for (int mt = 0; mt < 4; mt++) acc[mt] = (f32x4){0.f, 0.f, 0.f, 0.f};

#pragma unroll
    for (int kt = 0; kt < 13; kt++) {
#pragma unroll
        for (int mt = 0; mt < 4; mt++) {
            long a = *(const long*)(&fA[mt * 16 + l16][kt * 32 + g8]);
            acc[mt] = __builtin_amdgcn_mfma_f32_16x16x32_fp8_fp8(a, bfr[kt], acc[mt], 0, 0, 0);
        }
    }

    // ---- phase 3: LayerNorm stats. Reduce 16 cols in-wave, combine via LDS.
    float sum[4][4], ssq[4][4];
#pragma unroll
    for (int mt = 0; mt < 4; mt++)
#pragma unroll
        for (int r = 0; r < 4; r++) {
            float v = acc[mt][r];
            sum[mt][r] = v;
            ssq[mt][r] = v * v;
        }
#pragma unroll
    for (int off = 1; off < 16; off <<= 1)
#pragma unroll
        for (int mt = 0; mt < 4; mt++)
#pragma unroll
            for (int r = 0; r < 4; r++) {
                sum[mt][r] += __shfl_xor(sum[mt][r], off);
                ssq[mt][r] += __shfl_xor(ssq[mt][r], off);
            }

    __syncthreads();                        // all fA reads done -> reuse as scratch
    float* red     = (float*)&fA[0][0];     // [64 rows][8 waves][2] = 4 KB
    float* red2    = red + 1024;            // [64 rows][2] = 512 B
    float* staging = (float*)((char*)&fA[0][0] + 8192);  // 32 rows x 128 f32 = 16 KB
    int lg = lane >> 4;
    if (l16 == 0) {
#pragma unroll
        for (int mt = 0; mt < 4; mt++)
#pragma unroll
            for (int r = 0; r < 4; r++) {
                int row = mt * 16 + lg * 4 + r;
                red[(row * 8 + w) * 2 + 0] = sum[mt][r];
                red[(row * 8 + w) * 2 + 1] = ssq[mt][r];
            }
    }
    __syncthreads();
    if (t < 64) {
        float ts = 0.f, tq = 0.f;
#pragma unroll
        for (int u = 0; u < 8; u++) {
            ts += red[(t * 8 + u) * 2 + 0];
            tq += red[(t * 8 + u) * 2 + 1];
        }
        float mu  = ts * (1.0f / 128.0f);
        float var = tq * (1.0f / 128.0f) - mu * mu;
        red2[t * 2 + 0] = mu;
        red2[t * 2 + 1] = 1.0f / sqrtf(var + 1e-5f);
    }
    __syncthreads();

    // ---- phase 4: normalized epilogue via LDS staging, non-temporal full-line stores.
    float sc = lns[ncol + l16];
    float of = lno[ncol + l16];
    f32x4* Eout4 = (f32x4*)Eout;
#pragma unroll
    for (int h = 0; h < 2; h++) {
#pragma unroll
        for (int m2 = 0; m2 < 2; m2++) {
            int mt = 2 * h + m2;
#pragma unroll
            for (int r = 0; r < 4; r++) {
                int row  = mt * 16 + lg * 4 + r;      // global row in tile
                int lrow = row - 32 * h;              // 0..31
                float mu = red2[row * 2 + 0];
                float rs = red2[row * 2 + 1];
                staging[lrow * 128 + ncol + l16] =
                    sc * ((acc[mt][r] - mu) * rs) + of;
            }
        }
        __syncthreads();
        // stream out: 1024 f32x4 = 32 rows x 512B, consecutive threads -> consecutive 16B
#pragma unroll
        for (int u = 0; u < 2; u++) {
            int idx  = u * 512 + t;                   // 0..1023
            int lrow = idx >> 5;
            int c4   = idx & 31;
            f32x4 v = *(f32x4*)&staging[lrow * 128 + c4 * 4];
            __builtin_nontemporal_store(v, &Eout4[(size_t)(base + 32 * h + lrow) * 32 + c4]);
        }
        __syncthreads();
    }
}

extern "C" void kernel_launch(void* const* d_in, const int* in_sizes, int n_in,
                              void* d_out, int out_size, void* d_ws, size_t ws_size,
                              hipStream_t stream)
{
    const float* X    = (const float*)d_in[0];
    const float* mask = (const float*)d_in[1];
    const int*   ridx = (const int*)d_in[2];
    const int*   chl  = (const int*)d_in[3];
    const float* posW = (const float*)d_in[4];
    const float* posb = (const float*)d_in[5];
    const float* eW   = (const float*)d_in[6];
    const float* lns  = (const float*)d_in[7];
    const float* lno  = (const float*)d_in[8];

    float* Eout   = (float*)d_out;                                  // B*L*K*128
    float* eidx_f = Eout + (size_t)NB * NL * NK * NEF;              // B*L*K (as float)

    char* ws = (char*)d_ws;
    float4*        atoms5 = (float4*)ws;                            // 327680 B
    float*         dnb    = (float*)(ws + 327680);                  // 491520 B
    int*           eidx   = (int*)(ws + 819200);                    // 491520 B
    unsigned char* Wt     = (unsigned char*)(ws + 1310720);         // 53248 B
    float4*        caw4   = (float4*)(ws + 1363968);                // 65536 B

    k_atoms<<<(NB * NL + 255) / 256, 256, 0, stream>>>(X, mask, atoms5, caw4);
    k_wconv<<<(NEF * (NEIN/2) + 255) / 256, 256, 0, stream>>>(eW, Wt);
    k_topk<<<(NB * NL) / 4, 256, 0, stream>>>(caw4, dnb, eidx, eidx_f);
    k_edge<<<(NB * NL * NK) / BM, 512, 0, stream>>>(atoms5, eidx, dnb, ridx, chl,
                                                    posW, posb, Wt, lns, lno, Eout);
}

// Round 12
// 93.378 us; speedup vs baseline: 1.6756x; 1.0483x over previous
//
#include <hip/hip_runtime.h>
#include <math.h>

#define NB 2
#define NL 2048
#define NK 30
#define NEF 128
#define NEIN 416
#define BM 64            // edges per block in k_edge
#define FROW 424         // fA row stride (bytes): 8B-aligned, stride/4=106 -> quarter-wave
                         // b64 reads cover all 32 banks (432 covered only half)
#define SROW 132         // staging row stride (floats): 2-way on writes (free)

typedef float f32x4 __attribute__((ext_vector_type(4)));
typedef unsigned long long ull;

__constant__ int c_PA[24] = {0,2,3,4,1,1,1,1,0,0,0,4,4,3,0,2,3,4,2,3,4,2,3,2};
__constant__ int c_PB[24] = {0,2,3,4,0,2,3,4,2,3,4,2,3,2,1,1,1,1,0,0,0,4,4,3};

__device__ inline ull umin64(ull a, ull b) { return a < b ? a : b; }
__device__ inline ull umax64(ull a, ull b) { return a > b ? a : b; }

// ---- kernel 0 (merged): blocks 0..15 -> atoms5 + caw4 ; blocks 16.. -> Wt fp8 ----
__global__ void k_prep(const float* __restrict__ X, const float* __restrict__ mask,
                       const float* __restrict__ eW,
                       float4* __restrict__ atoms5, float4* __restrict__ caw4,
                       unsigned char* __restrict__ Wt)
{
    int t = threadIdx.x;
    if (blockIdx.x < 16) {
        int idx = blockIdx.x * 256 + t;           // 16*256 = 4096 = NB*NL exactly
        const float* x = X + (size_t)idx * 12;
        float N[3], Ca[3], C[3], O[3], bv[3], cv[3], av[3];
#pragma unroll
        for (int d = 0; d < 3; d++) { N[d] = x[d]; Ca[d] = x[3+d]; C[d] = x[6+d]; O[d] = x[9+d]; }
#pragma unroll
        for (int d = 0; d < 3; d++) { bv[d] = Ca[d] - N[d]; cv[d] = C[d] - Ca[d]; }
        av[0] = bv[1]*cv[2] - bv[2]*cv[1];
        av[1] = bv[2]*cv[0] - bv[0]*cv[2];
        av[2] = bv[0]*cv[1] - bv[1]*cv[0];
        float4* o = atoms5 + (size_t)idx * 5;
        o[0] = make_float4(N[0], N[1], N[2], 0.f);
        o[1] = make_float4(Ca[0], Ca[1], Ca[2], 0.f);
        o[2] = make_float4(C[0], C[1], C[2], 0.f);
        o[3] = make_float4(O[0], O[1], O[2], 0.f);
        float cb0 = -0.58273431f*av[0] + 0.56802827f*bv[0] - 0.54067466f*cv[0] + Ca[0];
        float cb1 = -0.58273431f*av[1] + 0.56802827f*bv[1] - 0.54067466f*cv[1] + Ca[1];
        float cb2 = -0.58273431f*av[2] + 0.56802827f*bv[2] - 0.54067466f*cv[2] + Ca[2];
        o[4] = make_float4(cb0, cb1, cb2, 0.f);
        caw4[idx] = make_float4(Ca[0], Ca[1], Ca[2], mask[idx]);
    } else {
        int idx = (blockIdx.x - 16) * 256 + t;    // 104*256 = 26624 = NEF*NEIN/2
        if (idx >= NEF * (NEIN / 2)) return;
        int c  = idx / (NEIN / 2);
        int k2 = idx - c * (NEIN / 2);
        float a = eW[(size_t)(2 * k2) * NEF + c];
        float b = eW[(size_t)(2 * k2 + 1) * NEF + c];
        int r = __builtin_amdgcn_cvt_pk_fp8_f32(a, b, 0, false);
        *(unsigned short*)&Wt[(size_t)c * NEIN + 2 * k2] = (unsigned short)(r & 0xffff);
    }
}

// ---- kernel 1: exact top-30, one WAVE per row, streaming 4-slot min-list ----
__global__ __launch_bounds__(256, 4) void k_topk(const float4* __restrict__ caw4,
                                                 float* __restrict__ dnb,
                                                 int*   __restrict__ eidx,
                                                 float* __restrict__ eidx_f)
{
    __shared__ float4 ca[NL];
    int t = threadIdx.x;
    int base = blockIdx.x << 2;          // 4 rows per block (one per wave)
    int b = base >> 11;
    const float4* src = caw4 + (size_t)b * NL;
#pragma unroll
    for (int r = 0; r < NL/256; r++) ca[t + r*256] = src[t + r*256];
    __syncthreads();

    int w = t >> 6, lane = t & 63;
    int row = base + w;
    int i = row & (NL - 1);
    float4 ci = ca[i];
    float mi = ci.w;

    float df[32];
    unsigned mflags = 0;
    float lmax = 0.0f;
#pragma unroll
    for (int r = 0; r < 32; r++) {
        float4 cj = ca[r*64 + lane];
        float dx = __fsub_rn(ci.x, cj.x);
        float dy = __fsub_rn(ci.y, cj.y);
        float dz = __fsub_rn(ci.z, cj.z);
        float s  = __fadd_rn(__fadd_rn(__fmul_rn(dx,dx), __fmul_rn(dy,dy)), __fmul_rn(dz,dz));
        s = __fadd_rn(s, 1e-6f);
        float m2 = __fmul_rn(mi, cj.w);   // binary mask: 0 or 1
        float d  = __fmul_rn(m2, __fsqrt_rn(s));
        df[r] = d;
        lmax = fmaxf(lmax, d);
        mflags |= (m2 != 0.0f) ? (1u << r) : 0u;
    }
#pragma unroll
    for (int off = 32; off; off >>= 1) lmax = fmaxf(lmax, __shfl_xor(lmax, off));
    unsigned rmb = __float_as_uint(lmax);

    const ull INF = ~0ULL;
    ull m0 = INF, m1 = INF, m2k = INF, m3 = INF;
#pragma unroll
    for (int r = 0; r < 32; r++) {
        unsigned hi = ((mflags >> r) & 1u) ? __float_as_uint(df[r]) : rmb;
        ull key = ((ull)hi << 32) | (unsigned)(r*64 + lane);
        ull a0 = umin64(key, m0); ull k1 = umax64(key, m0); m0 = a0;
        ull a1 = umin64(k1, m1);  ull k2 = umax64(k1, m1);  m1 = a1;
        ull a2 = umin64(k2, m2k); ull k3 = umax64(k2, m2k); m2k = a2;
        m3 = umin64(k3, m3);
    }

    int c = 0;
    ull mykey = 0;
    for (int sel = 0; sel < NK; sel++) {
        ull g = m0;
#pragma unroll
        for (int off = 32; off; off >>= 1) {
            ull o = __shfl_xor(g, off);
            g = o < g ? o : g;
        }
        if (m0 == g) {
            m0 = m1; m1 = m2k; m2k = m3; m3 = INF;
            c++;
            if (m0 == INF && c < 32) {
#pragma unroll
                for (int r = 0; r < 32; r++) {
                    unsigned hi = ((mflags >> r) & 1u) ? __float_as_uint(df[r]) : rmb;
                    ull key = ((ull)hi << 32) | (unsigned)(r*64 + lane);
                    if (key > g) {
                        ull a0 = umin64(key, m0); ull k1 = umax64(key, m0); m0 = a0;
                        ull a1 = umin64(k1, m1);  ull k2 = umax64(k1, m1);  m1 = a1;
                        ull a2 = umin64(k2, m2k); ull k3 = umax64(k2, m2k); m2k = a2;
                        m3 = umin64(k3, m3);
                    }
                }
            }
        }
        mykey = (lane == sel) ? g : mykey;
    }
    if (lane < NK) {
        int g = row * NK + lane;
        int j = (int)(mykey & 0xffffffffULL);
        dnb[g]    = __uint_as_float((unsigned)(mykey >> 32));
        eidx[g]   = j;
        eidx_f[g] = (float)j;
    }
}

// ------- kernel 2: features(fp8) + fp8 MFMA GEMM + LayerNorm, 512 thr / 8 waves -------
// FROW=424: conflict-free quarter-wave b64 A-reads (all 32 banks). B preloaded at
// kernel top (L2 latency hides under phase 1). NT full-line output stores.
__global__ __launch_bounds__(512, 4) void k_edge(const float4* __restrict__ atoms5,
                                              const int*   __restrict__ eidx,
                                              const float* __restrict__ dnb,
                                              const int*   __restrict__ ridx,
                                              const int*   __restrict__ chl,
                                              const float* __restrict__ posW,
                                              const float* __restrict__ posb,
                                              const unsigned char* __restrict__ Wt,
                                              const float* __restrict__ lns,
                                              const float* __restrict__ lno,
                                              float* __restrict__ Eout)
{
    __shared__ __align__(16) unsigned char fA[BM][FROW];   // 27136 B
    int t = threadIdx.x;
    int base = blockIdx.x * BM;

    int w    = t >> 6;
    int lane = t & 63;
    int l16  = lane & 15;
    int g8   = (lane >> 4) * 8;
    int ncol = w * 16;

    // ---- B preload FIRST: 13 x 8B independent loads; L2 latency hides under phase 1.
    const unsigned char* wtb = Wt + (size_t)(ncol + l16) * NEIN + g8;
    long bfr[13];
#pragma unroll
    for (int kt = 0; kt < 13; kt++)
        bfr[kt] = *(const long*)(wtb + kt * 32);

    // ---- phase 1: features, p-split, fp8-packed, b64-pair LDS writes.
    {
        int e = t >> 3;
        int q = t & 7;
        int g = base + e;
        int b = g / (NL * NK);
        int rem = g - b * (NL * NK);
        int i = rem / NK;
        int gi = b * NL + i;
        int j = eidx[g];
        int gj = b * NL + j;

        int off = ridx[gi] - ridx[gj];
        int ec  = (chl[gi] == chl[gj]) ? 1 : 0;
        int dp  = min(max(off + 32, 0), 64);
        dp = ec ? dp : 65;
        {
            float p0 = posW[dp * 16 + 2*q]     + posb[2*q];
            float p1 = posW[dp * 16 + 2*q + 1] + posb[2*q + 1];
            int r = __builtin_amdgcn_cvt_pk_fp8_f32(p0, p1, 0, false);
            *(unsigned short*)&fA[e][q * 2] = (unsigned short)(r & 0xffff);
        }

        const float4* A4 = atoms5 + (size_t)gi * 5;
        const float4* B4 = atoms5 + (size_t)gj * 5;

        auto body = [&](int p) {
            float D;
            if (p == 0) {
                D = dnb[g];
            } else {
                float4 a  = A4[c_PA[p - 1]];
                float4 bb = B4[c_PB[p - 1]];
                float dx = a.x - bb.x, dy = a.y - bb.y, dz = a.z - bb.z;
                D = sqrtf(dx*dx + dy*dy + dz*dz + 1e-6f);
            }
            float tD = D * 0.8f;                  // prescale: z = tD - mu*0.8
            int wds[4];
#pragma unroll
            for (int gq = 0; gq < 4; gq++) {
                float v[4];
#pragma unroll
                for (int u = 0; u < 4; u++) {
                    int s = gq * 4 + u;
                    float z = tD - (1.6f + (float)s * 1.06666667f);
                    v[u] = __expf(-(z * z));
                }
                int r = __builtin_amdgcn_cvt_pk_fp8_f32(v[0], v[1], 0, false);
                r = __builtin_amdgcn_cvt_pk_fp8_f32(v[2], v[3], r, true);
                wds[gq] = r;
            }
            long lo = ((long)(unsigned)wds[1] << 32) | (unsigned)wds[0];
            long hi = ((long)(unsigned)wds[3] << 32) | (unsigned)wds[2];
            *(long*)&fA[e][16 + p * 16]     = lo;
            *(long*)&fA[e][16 + p * 16 + 8] = hi;
        };

#pragma unroll
        for (int pp = 0; pp < 3; pp++) body(q + pp * 8);
        if (q == 0) body(24);
    }

    __syncthreads();

    // ---- phase 2: GEMM. 52 MFMA + 52 conflict-free ds_read_b64 per wave.
    f32x4 acc[4];
#pragma unroll
    for (int mt = 0; mt < 4; mt++) acc[mt] = (f32x4){0.f, 0.f, 0.f, 0.f};

#pragma unroll
    for (int kt = 0; kt < 13; kt++) {
#pragma unroll
        for (int mt = 0; mt < 4; mt++) {
            long a = *(const long*)(&fA[mt * 16 + l16][kt * 32 + g8]);
            acc[mt] = __builtin_amdgcn_mfma_f32_16x16x32_fp8_fp8(a, bfr[kt], acc[mt], 0, 0, 0);
        }
    }

    // ---- phase 3: LayerNorm stats. Reduce 16 cols in-wave, combine via LDS.
    float sum[4][4], ssq[4][4];
#pragma unroll
    for (int mt = 0; mt < 4; mt++)
#pragma unroll
        for (int r = 0; r < 4; r++) {
            float v = acc[mt][r];
            sum[mt][r] = v;
            ssq[mt][r] = v * v;
        }
#pragma unroll
    for (int off = 1; off < 16; off <<= 1)
#pragma unroll
        for (int mt = 0; mt < 4; mt++)
#pragma unroll
            for (int r = 0; r < 4; r++) {
                sum[mt][r] += __shfl_xor(sum[mt][r], off);
                ssq[mt][r] += __shfl_xor(ssq[mt][r], off);
            }

    __syncthreads();                        // all fA reads done -> reuse as scratch
    float* red     = (float*)&fA[0][0];     // [64 rows][8 waves][2] = 4 KB
    float* red2    = red + 1024;            // [64 rows][2] = 512 B
    float* staging = (float*)((char*)&fA[0][0] + 8192);  // 32 rows x SROW f32 = 16.9 KB
    int lg = lane >> 4;
    if (l16 == 0) {
#pragma unroll
        for (int mt = 0; mt < 4; mt++)
#pragma unroll
            for (int r = 0; r < 4; r++) {
                int row = mt * 16 + lg * 4 + r;
                red[(row * 8 + w) * 2 + 0] = sum[mt][r];
                red[(row * 8 + w) * 2 + 1] = ssq[mt][r];
            }
    }
    __syncthreads();
    if (t < 64) {
        float ts = 0.f, tq = 0.f;
#pragma unroll
        for (int u = 0; u < 8; u++) {
            ts += red[(t * 8 + u) * 2 + 0];
            tq += red[(t * 8 + u) * 2 + 1];
        }
        float mu  = ts * (1.0f / 128.0f);
        float var = tq * (1.0f / 128.0f) - mu * mu;
        red2[t * 2 + 0] = mu;
        red2[t * 2 + 1] = 1.0f / sqrtf(var + 1e-5f);
    }
    __syncthreads();

    // ---- phase 4: normalized epilogue via LDS staging, non-temporal full-line stores.
    float sc = lns[ncol + l16];
    float of = lno[ncol + l16];
    f32x4* Eout4 = (f32x4*)Eout;
#pragma unroll
    for (int h = 0; h < 2; h++) {
#pragma unroll
        for (int m2 = 0; m2 < 2; m2++) {
            int mt = 2 * h + m2;
#pragma unroll
            for (int r = 0; r < 4; r++) {
                int row  = mt * 16 + lg * 4 + r;      // global row in tile
                int lrow = row - 32 * h;              // 0..31
                float mu = red2[row * 2 + 0];
                float rs = red2[row * 2 + 1];
                staging[lrow * SROW + ncol + l16] =
                    sc * ((acc[mt][r] - mu) * rs) + of;
            }
        }
        __syncthreads();
        // stream out: 1024 f32x4 = 32 rows x 512B, consecutive threads -> consecutive 16B
#pragma unroll
        for (int u = 0; u < 2; u++) {
            int idx  = u * 512 + t;                   // 0..1023
            int lrow = idx >> 5;
            int c4   = idx & 31;
            f32x4 v = *(f32x4*)&staging[lrow * SROW + c4 * 4];
            __builtin_nontemporal_store(v, &Eout4[(size_t)(base + 32 * h + lrow) * 32 + c4]);
        }
        __syncthreads();
    }
}

extern "C" void kernel_launch(void* const* d_in, const int* in_sizes, int n_in,
                              void* d_out, int out_size, void* d_ws, size_t ws_size,
                              hipStream_t stream)
{
    const float* X    = (const float*)d_in[0];
    const float* mask = (const float*)d_in[1];
    const int*   ridx = (const int*)d_in[2];
    const int*   chl  = (const int*)d_in[3];
    const float* posW = (const float*)d_in[4];
    const float* posb = (const float*)d_in[5];
    const float* eW   = (const float*)d_in[6];
    const float* lns  = (const float*)d_in[7];
    const float* lno  = (const float*)d_in[8];

    float* Eout   = (float*)d_out;                                  // B*L*K*128
    float* eidx_f = Eout + (size_t)NB * NL * NK * NEF;              // B*L*K (as float)

    char* ws = (char*)d_ws;
    float4*        atoms5 = (float4*)ws;                            // 327680 B
    float*         dnb    = (float*)(ws + 327680);                  // 491520 B
    int*           eidx   = (int*)(ws + 819200);                    // 491520 B
    unsigned char* Wt     = (unsigned char*)(ws + 1310720);         // 53248 B
    float4*        caw4   = (float4*)(ws + 1363968);                // 65536 B

    k_prep<<<16 + (NEF * (NEIN/2) + 255) / 256, 256, 0, stream>>>(X, mask, eW, atoms5, caw4, Wt);
    k_topk<<<(NB * NL) / 4, 256, 0, stream>>>(caw4, dnb, eidx, eidx_f);
    k_edge<<<(NB * NL * NK) / BM, 512, 0, stream>>>(atoms5, eidx, dnb, ridx, chl,
                                                    posW, posb, Wt, lns, lno, Eout);
}